// Round 7
// baseline (1043.320 us; speedup 1.0000x reference)
//
#include <hip/hip_runtime.h>
#include <hip/hip_bf16.h>

#define LL 512
#define DD 1024
#define HH 8
#define DKK 128
#define QQ 256
#define CCC 128
#define TTT 128
#define RR 50
#define FFF 4096
#define KLD 576          // Kh rows per head: 512 keys + 50 embk + 12 ltabs + 2 pad
#define SLD 576          // (kept for workspace layout arithmetic)

typedef __attribute__((ext_vector_type(8))) short short8;
typedef __attribute__((ext_vector_type(4))) float float4v;

__device__ __forceinline__ unsigned short f2bu(float f) {
  __hip_bfloat16 h = __float2bfloat16(f);
  unsigned short u; __builtin_memcpy(&u, &h, 2); return u;
}
__device__ __forceinline__ float b2f(unsigned short u) {
  unsigned int v = ((unsigned int)u) << 16;
  float f; __builtin_memcpy(&f, &v, 4); return f;
}
__device__ __forceinline__ int4 cvt8(float4 x, float4 y) {
  int4 o;
  o.x = (int)f2bu(x.x) | ((int)f2bu(x.y) << 16);
  o.y = (int)f2bu(x.z) | ((int)f2bu(x.w) << 16);
  o.z = (int)f2bu(y.x) | ((int)f2bu(y.y) << 16);
  o.w = (int)f2bu(y.z) | ((int)f2bu(y.w) << 16);
  return o;
}

// barrier draining only LDS (lgkmcnt(0)); global loads stay in flight.
__device__ __forceinline__ void lds_barrier() {
  __builtin_amdgcn_sched_barrier(0);
  __builtin_amdgcn_s_waitcnt(0xC07F);
  __builtin_amdgcn_s_barrier();
  __builtin_amdgcn_sched_barrier(0);
}

// ---- grid barrier: one-shot counter, all 256 blocks resident (1/CU) ----
__device__ __forceinline__ void gbar(unsigned* slot) {
  __syncthreads();
  __threadfence();
  if (threadIdx.x == 0)
    __hip_atomic_fetch_add(slot, 1u, __ATOMIC_ACQ_REL, __HIP_MEMORY_SCOPE_AGENT);
  while (__hip_atomic_load(slot, __ATOMIC_ACQUIRE, __HIP_MEMORY_SCOPE_AGENT) < 256u)
    __builtin_amdgcn_s_sleep(2);
  __threadfence();
  __syncthreads();
}

// ---- K layout: slice-major [h][16 slices c][576 rows][8 elems] (bf16) ----
// ---- V layout: slice-major [h][64 slices c][128 d  ][8 elems] (bf16) ----

#define ABYTES8 (128*128)
#define TILE8 (ABYTES8 + 64*128)

// 8-wave GEMM staging: A bf16 2 int4/thread, B fp32 2 float4 -> cvt8.
#define GLOAD(A0,A1,F0,F1,itv) { int k0v = (itv) << 6;                        \
  A0 = *(const int4*)(Az + (size_t)(bm + r)*lda + k0v + gc*8);                \
  A1 = *(const int4*)(Az + (size_t)(bm + 64 + r)*lda + k0v + gc*8);           \
  F0 = *(const float4*)(Bz32 + (size_t)r*ldb + k0v + gc*8);                   \
  F1 = *(const float4*)(Bz32 + (size_t)r*ldb + k0v + gc*8 + 4); }

#define GSTORE(basep,A0,A1,F0,F1) { char* bse = (basep);                      \
  *(int4*)(bse + r*128 + sl*16) = A0;                                         \
  *(int4*)(bse + (64 + r)*128 + sl*16) = A1;                                  \
  *(int4*)(bse + ABYTES8 + r*128 + sl*16) = cvt8(F0, F1); }

#define GEMM8_KLOOP()                                                         \
  GLOAD(Aa0,Aa1,Af0,Af1, 0);                                                  \
  GLOAD(Ba0,Ba1,Bf0,Bf1, 1);                                                  \
  GLOAD(Ca0,Ca1,Cf0,Cf1, 2);                                                  \
  GLOAD(Da0,Da1,Df0,Df1, 3);                                                  \
  for (int it = 0; it < nit; it += 4) {                                       \
    GSTORE(lds, Aa0,Aa1,Af0,Af1);                                             \
    if (it + 4 < nit) GLOAD(Aa0,Aa1,Af0,Af1, it+4);                           \
    lds_barrier();                                                            \
    compute(lds);                                                             \
    GSTORE(lds + TILE8, Ba0,Ba1,Bf0,Bf1);                                     \
    if (it + 5 < nit) GLOAD(Ba0,Ba1,Bf0,Bf1, it+5);                           \
    lds_barrier();                                                            \
    compute(lds + TILE8);                                                     \
    GSTORE(lds, Ca0,Ca1,Cf0,Cf1);                                             \
    if (it + 6 < nit) GLOAD(Ca0,Ca1,Cf0,Cf1, it+6);                           \
    lds_barrier();                                                            \
    compute(lds);                                                             \
    GSTORE(lds + TILE8, Da0,Da1,Df0,Df1);                                     \
    if (it + 7 < nit) GLOAD(Da0,Da1,Df0,Df1, it+7);                           \
    lds_barrier();                                                            \
    compute(lds + TILE8);                                                     \
  }

#define GEMM8_PREAMBLE()                                                      \
  const int w = t >> 6, l = t & 63;                                           \
  const int wm = (w>>1)*32, wn = (w&1)*32;                                    \
  float4v acc[2][2];                                                          \
  _Pragma("unroll")                                                           \
  for (int m=0;m<2;++m)                                                       \
    _Pragma("unroll")                                                         \
    for (int n=0;n<2;++n) acc[m][n] = (float4v){0.f,0.f,0.f,0.f};             \
  const int r = t >> 3, sl = t & 7;                                           \
  const int gc = sl ^ (r & 7);                                                \
  const int quad = l >> 4, lrow = l & 15;                                     \
  int4 Aa0, Aa1;  float4 Af0, Af1;                                            \
  int4 Ba0, Ba1;  float4 Bf0, Bf1;                                            \
  int4 Ca0, Ca1;  float4 Cf0, Cf1;                                            \
  int4 Da0, Da1;  float4 Df0, Df1;                                            \
  auto compute = [&](const char* base) {                                      \
    const char* ab = base;                                                    \
    const char* bb = base + ABYTES8;                                          \
    _Pragma("unroll")                                                         \
    for (int step=0; step<2; ++step) {                                        \
      int c = step*4 + quad;                                                  \
      short8 af[2], bf[2];                                                    \
      _Pragma("unroll")                                                       \
      for (int m=0;m<2;++m) {                                                 \
        int Rw = wm + m*16 + lrow;                                            \
        af[m] = *(const short8*)(ab + Rw*128 + ((c ^ (Rw & 7))*16));          \
      }                                                                       \
      _Pragma("unroll")                                                       \
      for (int n=0;n<2;++n) {                                                 \
        int Rw = wn + n*16 + lrow;                                            \
        bf[n] = *(const short8*)(bb + Rw*128 + ((c ^ (Rw & 7))*16));          \
      }                                                                       \
      _Pragma("unroll")                                                       \
      for (int m=0;m<2;++m)                                                   \
        _Pragma("unroll")                                                     \
        for (int n=0;n<2;++n)                                                 \
          acc[m][n] = __builtin_amdgcn_mfma_f32_16x16x32_bf16(af[m], bf[n], acc[m][n], 0, 0, 0); \
    }                                                                         \
  };

// ---- standard-epilogue 8-wave GEMM (B fp32 direct) ----
template<int ZK, int OUT_BF16, int RELU, int HAS_SRC, int HAS_BIAS>
__device__ __forceinline__ void gemm8_dev(char* lds, int t,
    const unsigned short* __restrict__ Az, int lda,
    const float* __restrict__ Bz32, int ldb,
    const float* __restrict__ bias,
    const float* __restrict__ src, int ldsrc,
    void* __restrict__ Cv, int ldc,
    int bm, int bn, int nit)
{
  GEMM8_PREAMBLE();
  GEMM8_KLOOP();
  #pragma unroll
  for (int m=0;m<2;++m)
    #pragma unroll
    for (int n=0;n<2;++n)
      #pragma unroll
      for (int rg=0;rg<4;++rg) {
        int row = bm + wm + m*16 + quad*4 + rg;
        int col = bn + wn + n*16 + lrow;
        float vv = acc[m][n][rg];
        if (ZK) {
          atomicAdd(&((float*)Cv)[(size_t)row*ldc + col], vv);
        } else {
          if (HAS_BIAS) vv += bias[col];
          if (HAS_SRC)  vv += src[(size_t)row*ldsrc + col];
          if (RELU) vv = fmaxf(vv, 0.f);
          if (OUT_BF16) ((unsigned short*)Cv)[(size_t)row*ldc + col] = f2bu(vv);
          else          ((float*)Cv)[(size_t)row*ldc + col] = vv;
        }
      }
}

// ---- QKV-scatter 8-wave GEMM ----
__device__ __forceinline__ void gemm8_qkv_dev(char* lds, int t,
    const unsigned short* __restrict__ Az, int lda,
    const float* __restrict__ Bz32, int ldb,
    const float* __restrict__ bq, const float* __restrict__ bk,
    const float* __restrict__ bv,
    unsigned short* __restrict__ Qh, unsigned short* __restrict__ Kh,
    unsigned short* __restrict__ Vt,
    int bm, int bn, int nit)
{
  GEMM8_PREAMBLE();
  GEMM8_KLOOP();
  #pragma unroll
  for (int m=0;m<2;++m)
    #pragma unroll
    for (int n=0;n<2;++n)
      #pragma unroll
      for (int rg=0;rg<4;++rg) {
        int row = bm + wm + m*16 + quad*4 + rg;
        int col = bn + wn + n*16 + lrow;
        int part = col >> 10, hh = (col >> 7) & 7, d = col & 127;
        const float* bp = (part==0) ? bq : (part==1) ? bk : bv;
        float vv = acc[m][n][rg] + bp[col & 1023];
        unsigned short o = f2bu(vv);
        if (part == 0)      Qh[((size_t)hh*LL + row)*DKK + d] = o;
        else if (part == 1) Kh[(((size_t)hh*16 + (d>>3))*KLD + row)*8 + (d&7)] = o;
        else                Vt[(((size_t)hh*64 + (row>>3))*128 + d)*8 + (row&7)] = o;
      }
}

// ---- LayerNorm over one 1024-row with 512 threads (float2/thread) ----
__device__ __forceinline__ void ln_dev(char* lds, int t,
    const float* __restrict__ xr, const float* __restrict__ g,
    const float* __restrict__ b, unsigned short* __restrict__ yr,
    float* __restrict__ xw, const float* __restrict__ b2)
{
  const float2 xv = ((const float2*)xr)[t];
  float s = xv.x + xv.y, ss = xv.x*xv.x + xv.y*xv.y;
  #pragma unroll
  for (int off = 32; off >= 1; off >>= 1) {
    s += __shfl_xor(s, off); ss += __shfl_xor(ss, off);
  }
  float* red = (float*)lds;
  __syncthreads();
  if ((t & 63) == 0) { red[t >> 6] = s; red[8 + (t >> 6)] = ss; }
  __syncthreads();
  float S = 0.f, SS = 0.f;
  #pragma unroll
  for (int k2 = 0; k2 < 8; ++k2) { S += red[k2]; SS += red[8 + k2]; }
  float mean = S * (1.0f/DD);
  float var  = SS * (1.0f/DD) - mean*mean;
  float inv  = rsqrtf(var + 1e-5f);
  float2 gv = ((const float2*)g)[t], bv = ((const float2*)b)[t];
  ushort2 ov;
  ov.x = f2bu((xv.x-mean)*inv*gv.x + bv.x);
  ov.y = f2bu((xv.y-mean)*inv*gv.y + bv.y);
  ((ushort2*)yr)[t] = ov;
  if (b2) {
    float2 b2v = ((const float2*)b2)[t];
    float2 nx; nx.x = xv.x + b2v.x; nx.y = xv.y + b2v.y;
    ((float2*)xw)[t] = nx;
  }
  __syncthreads();
}

// ======== fused attention unit (v4 math, verbatim): 512 thr / 8 waves =======
#define A3_QROWB 272
#define A3_PROWB 1040
#define A3_SROWD 584
#define A3_O2ROW 132
#define A3_OFF_P   2176
#define A3_OFF_S   10496
#define A3_OFF_PW  29184
#define A3_OFF_PF1 30848
#define A3_OFF_PF2 30976
#define A3_OFF_SI  31104
#define A3_OFF_O2  31136

__device__ __forceinline__ void attn_dev(char* lds, int t, int unit,
    const unsigned short* __restrict__ Qh, const unsigned short* __restrict__ Kh,
    const unsigned short* __restrict__ Vt,
    const float* __restrict__ qcr, const float* __restrict__ cqr,
    const float* __restrict__ qtr, const float* __restrict__ tqr,
    const int* __restrict__ ct, const int* __restrict__ pred,
    const int* __restrict__ mask,
    const float* __restrict__ embv, const float* __restrict__ lqc_v,
    const float* __restrict__ lcq_v, const float* __restrict__ lqt_v,
    const float* __restrict__ ltq_v,
    unsigned short* __restrict__ obuf)
{
  const int w = t >> 6, l = t & 63, quad = l >> 4, lrow = l & 15;
  const int i0 = (unit & 63) * 8, h = unit >> 6;

  // zero pws/pf/sinv region (488 floats)
  for (int k2 = t; k2 < 488; k2 += 512) ((float*)(lds + A3_OFF_PW))[k2] = 0.f;

  // stage Q tile [8][128]
  if (t < 128) {
    int qr = t >> 4, qc = t & 15;
    *(int4*)(lds + qr*A3_QROWB + qc*16) =
        *(const int4*)(Qh + ((size_t)h*LL + i0 + qr)*DKK + qc*8);
  }
  lds_barrier();    // barrier 1: Qt + zeroed pws visible

  // ---- phase 1: S[8][576] = Q @ Kh^T, K fragments direct from global ----
  {
    const unsigned short* Kc = Kh + (size_t)h*16*KLD*8;
    short8 af0 = *(const short8*)(lds + lrow*A3_QROWB + (quad     )*16);
    short8 af1 = *(const short8*)(lds + lrow*A3_QROWB + (quad +  4)*16);
    short8 af2 = *(const short8*)(lds + lrow*A3_QROWB + (quad +  8)*16);
    short8 af3 = *(const short8*)(lds + lrow*A3_QROWB + (quad + 12)*16);
    #pragma unroll
    for (int s = w; s < 36; s += 8) {
      float4v acc = (float4v){0.f,0.f,0.f,0.f};
      int krow = s*16 + lrow;
      short8 bf0 = *(const short8*)(Kc + ((size_t)(quad     )*KLD + krow)*8);
      short8 bf1 = *(const short8*)(Kc + ((size_t)(quad +  4)*KLD + krow)*8);
      short8 bf2 = *(const short8*)(Kc + ((size_t)(quad +  8)*KLD + krow)*8);
      short8 bf3 = *(const short8*)(Kc + ((size_t)(quad + 12)*KLD + krow)*8);
      acc = __builtin_amdgcn_mfma_f32_16x16x32_bf16(af0, bf0, acc, 0, 0, 0);
      acc = __builtin_amdgcn_mfma_f32_16x16x32_bf16(af1, bf1, acc, 0, 0, 0);
      acc = __builtin_amdgcn_mfma_f32_16x16x32_bf16(af2, bf2, acc, 0, 0, 0);
      acc = __builtin_amdgcn_mfma_f32_16x16x32_bf16(af3, bf3, acc, 0, 0, 0);
      if (quad < 2) {
        #pragma unroll
        for (int rg = 0; rg < 4; ++rg)
          ((float*)(lds + A3_OFF_S))[(quad*4 + rg)*A3_SROWD + s*16 + lrow] = acc[rg];
      }
    }
  }
  lds_barrier();    // barrier 2: S visible

  // ---- phase 2: single-pass unnormalized softmax (64 lanes per row) ----
  const int row = t >> 6, l64 = t & 63;
  const int i = i0 + row;
  const float* Sp = (const float*)(lds + A3_OFF_S) + row*A3_SROWD;
  const int bse = (i0 < QQ) ? 562 : (i0 < QQ + CCC) ? 568 : 571;
  const float lq1a = Sp[bse], lq1b = Sp[bse+1], lq1c = Sp[bse+2];
  const float lq2a = Sp[565], lq2b = Sp[566], lq2c = Sp[567];

  float sum=0.f, f0=0.f, f1=0.f, f2=0.f, g0=0.f, g1=0.f, g2=0.f;
  float* pwsrow = (float*)(lds + A3_OFF_PW) + row*52;
  #pragma unroll
  for (int m = 0; m < 8; ++m) {
    int j = m*64 + l64;
    int predv = pred[i*LL + j];
    int maskv = mask[i*LL + j];
    float s = Sp[j] + Sp[512 + predv];
    float c0=0.f, c1=0.f, c2=0.f; int rt; int scat2 = 0;
    if (i0 < QQ) {
      if (j < QQ) { s += Sp[512]; rt = 0; }
      else if (j < QQ + CCC) {
        const float* r3 = qcr + ((size_t)i*CCC + (j - QQ))*3;
        c0 = r3[0]; c1 = r3[1]; c2 = r3[2];
        s += c0*lq1a + c1*lq1b + c2*lq1c; rt = 1;
      } else {
        const float* r3 = qtr + ((size_t)i*TTT + (j - QQ - CCC))*3;
        c0 = r3[0]; c1 = r3[1]; c2 = r3[2];
        s += c0*lq2a + c1*lq2b + c2*lq2c; rt = 2;
      }
    } else {
      if (j < QQ) {
        const float* r3 = (i < QQ + CCC) ? cqr + ((size_t)(i - QQ)*QQ + j)*3
                                         : tqr + ((size_t)(i - QQ - CCC)*QQ + j)*3;
        c0 = r3[0]; c1 = r3[1]; c2 = r3[2];
        s += c0*lq1a + c1*lq1b + c2*lq1c; rt = 1;
      } else {
        scat2 = ct[(i - QQ)*(CCC + TTT) + (j - QQ)];
        s += Sp[512 + scat2]; rt = 0;
      }
    }
    s *= 0.08838834764831845f;
    float e = (maskv == 0) ? 0.f : __expf(s);
    sum += e;
    *(unsigned short*)(lds + A3_OFF_P + row*A3_PROWB + j*2) = f2bu(e);
    atomicAdd(pwsrow + predv, e);
    if (rt == 0)      atomicAdd(pwsrow + scat2, e);
    else if (rt == 1) { f0 += e*c0; f1 += e*c1; f2 += e*c2; }
    else              { g0 += e*c0; g1 += e*c1; g2 += e*c2; }
  }
  #pragma unroll
  for (int off = 32; off >= 1; off >>= 1) {
    sum += __shfl_xor(sum, off);
    f0 += __shfl_xor(f0, off); f1 += __shfl_xor(f1, off); f2 += __shfl_xor(f2, off);
    g0 += __shfl_xor(g0, off); g1 += __shfl_xor(g1, off); g2 += __shfl_xor(g2, off);
  }
  if (l64 == 0) {
    float* pf1 = (float*)(lds + A3_OFF_PF1) + row*4;
    float* pf2 = (float*)(lds + A3_OFF_PF2) + row*4;
    pf1[0] = f0; pf1[1] = f1; pf1[2] = f2;
    pf2[0] = g0; pf2[1] = g1; pf2[2] = g2;
    ((float*)(lds + A3_OFF_SI))[row] = 1.0f / sum;
  }
  lds_barrier();    // barrier 3: P/pws/pf/sinv visible; S reads done

  // ---- o2term: o2s[row][d] = pws@embv + pf@tables (f32), 2 floats/thread ----
  {
    int orow = t >> 6, d0 = (t & 63)*2;
    const float* pwsr = (const float*)(lds + A3_OFF_PW) + orow*52;
    float a0=0.f, a1=0.f;
    #pragma unroll 5
    for (int rr = 0; rr < RR; ++rr) {
      float pv = pwsr[rr];
      float2 ev = *(const float2*)(embv + rr*DKK + d0);
      a0 += pv*ev.x; a1 += pv*ev.y;
    }
    const float* tab1 = (i0 < QQ) ? lqc_v : (i0 < QQ + CCC) ? lcq_v : ltq_v;
    const float* pf1 = (const float*)(lds + A3_OFF_PF1) + orow*4;
    float2 t0 = *(const float2*)(tab1 + d0);
    float2 t1 = *(const float2*)(tab1 + DKK + d0);
    float2 t2 = *(const float2*)(tab1 + 2*DKK + d0);
    a0 += pf1[0]*t0.x + pf1[1]*t1.x + pf1[2]*t2.x;
    a1 += pf1[0]*t0.y + pf1[1]*t1.y + pf1[2]*t2.y;
    if (i0 < QQ) {
      const float* pf2 = (const float*)(lds + A3_OFF_PF2) + orow*4;
      float2 u0 = *(const float2*)(lqt_v + d0);
      float2 u1 = *(const float2*)(lqt_v + DKK + d0);
      float2 u2 = *(const float2*)(lqt_v + 2*DKK + d0);
      a0 += pf2[0]*u0.x + pf2[1]*u1.x + pf2[2]*u2.x;
      a1 += pf2[0]*u0.y + pf2[1]*u1.y + pf2[2]*u2.y;
    }
    float2 av; av.x=a0; av.y=a1;
    *(float2*)((float*)(lds + A3_OFF_O2) + orow*A3_O2ROW + d0) = av;
  }
  lds_barrier();    // barrier 4: o2s visible

  // ---- phase 3: O[8][128] = E @ V^T; wave w owns d-cols [w*16, w*16+16) ----
  float4v oacc = (float4v){0.f,0.f,0.f,0.f};
  {
    const unsigned short* Vc = Vt + (size_t)h*64*128*8;
    #pragma unroll
    for (int it = 0; it < 8; ++it) {
      #pragma unroll
      for (int kk = 0; kk < 2; ++kk) {
        int c = kk*4 + quad;
        short8 pa = *(const short8*)(lds + A3_OFF_P + lrow*A3_PROWB + it*128 + c*16);
        short8 vf = *(const short8*)(Vc + (((size_t)(it*8 + c))*128 + w*16 + lrow)*8);
        oacc = __builtin_amdgcn_mfma_f32_16x16x32_bf16(pa, vf, oacc, 0, 0, 0);
      }
    }
  }

  // ---- epilogue: (oacc + o2s) * sinv -> obuf bf16 ----
  if (quad < 2) {
    const float* o2s = (const float*)(lds + A3_OFF_O2);
    const float* sinv = (const float*)(lds + A3_OFF_SI);
    int d = w*16 + lrow;
    #pragma unroll
    for (int rg = 0; rg < 4; ++rg) {
      int rw = quad*4 + rg;
      float val = (oacc[rg] + o2s[rw*A3_O2ROW + d]) * sinv[rw];
      obuf[(size_t)(i0 + rw)*DD + h*DKK + d] = f2bu(val);
    }
  }
  lds_barrier();    // protect LDS reads from next unit's zeroing
}

// ======== persistent mega-kernel: all 7 phases, 6 grid barriers ========
__global__ __launch_bounds__(512) void encoder_mega(
    const float* __restrict__ x,
    const float* __restrict__ qcr, const float* __restrict__ cqr,
    const float* __restrict__ qtr, const float* __restrict__ tqr,
    const int* __restrict__ ct, const int* __restrict__ pred,
    const int* __restrict__ mask,
    const float* __restrict__ embk, const float* __restrict__ embv,
    const float* __restrict__ lqc_k, const float* __restrict__ lqc_v,
    const float* __restrict__ lcq_k, const float* __restrict__ lcq_v,
    const float* __restrict__ lqt_k, const float* __restrict__ lqt_v,
    const float* __restrict__ ltq_k, const float* __restrict__ ltq_v,
    const float* __restrict__ Wq, const float* __restrict__ bq,
    const float* __restrict__ Wk, const float* __restrict__ bk,
    const float* __restrict__ Wv, const float* __restrict__ bv,
    const float* __restrict__ Wo, const float* __restrict__ bo,
    const float* __restrict__ ln1_g, const float* __restrict__ ln1_b,
    const float* __restrict__ ln2_g, const float* __restrict__ ln2_b,
    const float* __restrict__ W1, const float* __restrict__ b1,
    const float* __restrict__ W2, const float* __restrict__ b2,
    unsigned short* __restrict__ ybuf, unsigned short* __restrict__ obuf,
    unsigned short* __restrict__ Qh, unsigned short* __restrict__ Kh,
    unsigned short* __restrict__ Vt, unsigned short* __restrict__ hidden,
    float* __restrict__ out, unsigned* __restrict__ bar)
{
  __shared__ __align__(16) char lds[2*TILE8];
  const int bid = blockIdx.x, t = threadIdx.x;

  // ---- P0: LN1 (2 rows/block) + kprep (Kh rows 512..575) ----
  #pragma unroll
  for (int r2 = 0; r2 < 2; ++r2) {
    int row = bid + r2*256;
    ln_dev(lds, t, x + (size_t)row*DD, ln1_g, ln1_b,
           ybuf + (size_t)row*DD, nullptr, nullptr);
  }
  if (t < 256) {
    int gg = bid*256 + t;     // 256 blocks * 256 = 65536 = 8*64*128
    int d = gg & 127, rr = (gg >> 7) & 63, hh = gg >> 13;
    float v = 0.f;
    if (rr < 50) v = embk[rr*128 + d];
    else if (rr < 62) {
      int u = rr - 50; int tb = u/3, f = u - tb*3;
      const float* tab = (tb==0) ? lqc_k : (tb==1) ? lqt_k : (tb==2) ? lcq_k : ltq_k;
      v = tab[f*128 + d];
    }
    Kh[(((size_t)hh*16 + (d>>3))*KLD + 512 + rr)*8 + (d&7)] = f2bu(v);
  }
  gbar(bar + 0*16);

  // ---- P1: QKV GEMM (192 tiles of 128x64) with head scatter ----
  if (bid < 192) {
    int bx = bid % 48, by = bid / 48;
    int bm = by*128, bn = bx*64;
    int part0 = bn >> 10;
    const float* Bz32 = (part0==0 ? Wq : part0==1 ? Wk : Wv) + (size_t)(bn & 1023)*DD;
    gemm8_qkv_dev(lds, t, ybuf, DD, Bz32, DD, bq, bk, bv, Qh, Kh, Vt, bm, bn, 16);
  }
  gbar(bar + 1*16);

  // ---- P2: fused attention, 2 units/block (512 units total) ----
  #pragma unroll
  for (int uu = 0; uu < 2; ++uu)
    attn_dev(lds, t, bid + uu*256, Qh, Kh, Vt, qcr, cqr, qtr, tqr, ct, pred,
             mask, embv, lqc_v, lcq_v, lqt_v, ltq_v, obuf);
  gbar(bar + 2*16);

  // ---- P3: out-proj Wo + bo + residual(x) -> out (64 tiles) ----
  if (bid < 64) {
    int bm = (bid >> 4)*128, bn = (bid & 15)*64;
    gemm8_dev<0,0,0,1,1>(lds, t, obuf, DD, Wo + (size_t)bn*DD, DD,
                         bo, x, DD, out, DD, bm, bn, 16);
  }
  gbar(bar + 3*16);

  // ---- P4: LN2 -> ybuf bf16, out += b2 (2 rows/block) ----
  #pragma unroll
  for (int r2 = 0; r2 < 2; ++r2) {
    int row = bid + r2*256;
    ln_dev(lds, t, out + (size_t)row*DD, ln2_g, ln2_b,
           ybuf + (size_t)row*DD, out + (size_t)row*DD, b2);
  }
  gbar(bar + 4*16);

  // ---- P5: FFN1 relu -> hidden bf16 (256 tiles exactly) ----
  {
    int bm = (bid >> 6)*128, bn = (bid & 63)*64;
    gemm8_dev<0,1,1,0,1>(lds, t, ybuf, DD, W1 + (size_t)bn*DD, DD,
                         b1, nullptr, 0, hidden, FFF, bm, bn, 16);
  }
  gbar(bar + 5*16);

  // ---- P6: FFN2 split-K x4, atomicAdd -> out (256 blocks exactly) ----
  {
    int z = bid >> 6, tile = bid & 63;
    int bm = (tile >> 4)*128, bn = (tile & 15)*64;
    gemm8_dev<1,0,0,0,0>(lds, t, hidden + (size_t)z*1024, FFF,
                         W2 + (size_t)bn*FFF + (size_t)z*1024, FFF,
                         nullptr, nullptr, 0, out, DD, bm, bn, 16);
  }
}

// ---------------- launch ----------------
extern "C" void kernel_launch(void* const* d_in, const int* in_sizes, int n_in,
                              void* d_out, int out_size, void* d_ws, size_t ws_size,
                              hipStream_t stream)
{
  const float* x    = (const float*)d_in[0];
  const float* qcr  = (const float*)d_in[1];
  const float* cqr  = (const float*)d_in[2];
  const float* qtr  = (const float*)d_in[3];
  const float* tqr  = (const float*)d_in[4];
  const int*   ct   = (const int*)d_in[5];
  const int*   pred = (const int*)d_in[6];
  const int*   mask = (const int*)d_in[7];
  const float* embk = (const float*)d_in[8];
  const float* embv = (const float*)d_in[9];
  const float* lqc_k = (const float*)d_in[10];
  const float* lqc_v = (const float*)d_in[11];
  const float* lcq_k = (const float*)d_in[12];
  const float* lcq_v = (const float*)d_in[13];
  const float* lqt_k = (const float*)d_in[14];
  const float* lqt_v = (const float*)d_in[15];
  const float* ltq_k = (const float*)d_in[16];
  const float* ltq_v = (const float*)d_in[17];
  const float* Wq = (const float*)d_in[18]; const float* bq = (const float*)d_in[19];
  const float* Wk = (const float*)d_in[20]; const float* bk = (const float*)d_in[21];
  const float* Wv = (const float*)d_in[22]; const float* bv = (const float*)d_in[23];
  const float* Wo = (const float*)d_in[24]; const float* bo = (const float*)d_in[25];
  const float* ln1_g = (const float*)d_in[26]; const float* ln1_b = (const float*)d_in[27];
  const float* ln2_g = (const float*)d_in[28]; const float* ln2_b = (const float*)d_in[29];
  const float* W1 = (const float*)d_in[30]; const float* b1 = (const float*)d_in[31];
  const float* W2 = (const float*)d_in[32]; const float* b2 = (const float*)d_in[33];
  float* out = (float*)d_out;

  float* wsf = (float*)d_ws;
  float* S    = wsf;                          // FFN hidden region
  float* o2   = S + (size_t)HH*LL*SLD;        // layout stability (unused)
  unsigned short* ub = (unsigned short*)(o2 + (size_t)HH*LL*DKK);
  unsigned short* ybuf_b = ub;                        // [L,D]
  unsigned short* obuf_b = ybuf_b + LL*DD;            // [L,D]
  unsigned short* Qh     = obuf_b + LL*DD;            // [H][512][128]
  unsigned short* Kh     = Qh + (size_t)HH*LL*DKK;    // [H][16][576][8] slice-major
  unsigned short* Vt     = Kh + (size_t)HH*KLD*DKK;   // [H][64][128][8] slice-major
  unsigned short* hidden = (unsigned short*)S;        // [L][FFF] bf16
  unsigned* bar = (unsigned*)((char*)d_ws + ((ws_size - 1024) & ~(size_t)255));

  hipMemsetAsync(bar, 0, 1024, stream);
  encoder_mega<<<256, 512, 0, stream>>>(
      x, qcr, cqr, qtr, tqr, ct, pred, mask, embk, embv,
      lqc_k, lqc_v, lcq_k, lcq_v, lqt_k, lqt_v, ltq_k, ltq_v,
      Wq, bq, Wk, bk, Wv, bv, Wo, bo,
      ln1_g, ln1_b, ln2_g, ln2_b, W1, b1, W2, b2,
      ybuf_b, obuf_b, Qh, Kh, Vt, hidden, out, bar);
}

// Round 8
// 773.869 us; speedup vs baseline: 1.3482x; 1.3482x over previous
//
#include <hip/hip_runtime.h>
#include <hip/hip_bf16.h>

#define LL 512
#define DD 1024
#define HH 8
#define DKK 128
#define QQ 256
#define CCC 128
#define TTT 128
#define RR 50
#define FFF 4096
#define KLD 576          // Kh rows per head: 512 keys + 50 embk + 12 ltabs + 2 pad
#define SLD 576          // (kept for workspace layout arithmetic)

typedef __attribute__((ext_vector_type(8))) short short8;
typedef __attribute__((ext_vector_type(4))) float float4v;

__device__ __forceinline__ unsigned short f2bu(float f) {
  __hip_bfloat16 h = __float2bfloat16(f);
  unsigned short u; __builtin_memcpy(&u, &h, 2); return u;
}
__device__ __forceinline__ float b2f(unsigned short u) {
  unsigned int v = ((unsigned int)u) << 16;
  float f; __builtin_memcpy(&f, &v, 4); return f;
}
__device__ __forceinline__ int4 cvt8(float4 x, float4 y) {
  int4 o;
  o.x = (int)f2bu(x.x) | ((int)f2bu(x.y) << 16);
  o.y = (int)f2bu(x.z) | ((int)f2bu(x.w) << 16);
  o.z = (int)f2bu(y.x) | ((int)f2bu(y.y) << 16);
  o.w = (int)f2bu(y.z) | ((int)f2bu(y.w) << 16);
  return o;
}

// barrier draining only LDS (lgkmcnt(0)); global loads stay in flight.
__device__ __forceinline__ void lds_barrier() {
  __builtin_amdgcn_sched_barrier(0);
  __builtin_amdgcn_s_waitcnt(0xC07F);
  __builtin_amdgcn_s_barrier();
  __builtin_amdgcn_sched_barrier(0);
}

// ---- grid barrier: one-shot counter, all 256 blocks resident (1/CU) ----
// ONLY thread 0 of each block arrives+polls (R7's all-thread poll storm was
// ~10 coherent-point transactions/cycle to one line -> 930us kernel).
__device__ __forceinline__ void gbar(unsigned* slot) {
  __syncthreads();
  __threadfence();
  if (threadIdx.x == 0) {
    __hip_atomic_fetch_add(slot, 1u, __ATOMIC_ACQ_REL, __HIP_MEMORY_SCOPE_AGENT);
    while (__hip_atomic_load(slot, __ATOMIC_ACQUIRE, __HIP_MEMORY_SCOPE_AGENT) < 256u)
      __builtin_amdgcn_s_sleep(8);
  }
  __syncthreads();
  __threadfence();
}

// ---- K layout: slice-major [h][16 slices c][576 rows][8 elems] (bf16) ----
// ---- V layout: slice-major [h][64 slices c][128 d  ][8 elems] (bf16) ----

#define ABYTES8 (128*128)
#define TILE8 (ABYTES8 + 64*128)

// 8-wave GEMM staging: A bf16 2 int4/thread, B fp32 2 float4 -> cvt8.
#define GLOAD(A0,A1,F0,F1,itv) { int k0v = (itv) << 6;                        \
  A0 = *(const int4*)(Az + (size_t)(bm + r)*lda + k0v + gc*8);                \
  A1 = *(const int4*)(Az + (size_t)(bm + 64 + r)*lda + k0v + gc*8);           \
  F0 = *(const float4*)(Bz32 + (size_t)r*ldb + k0v + gc*8);                   \
  F1 = *(const float4*)(Bz32 + (size_t)r*ldb + k0v + gc*8 + 4); }

#define GSTORE(basep,A0,A1,F0,F1) { char* bse = (basep);                      \
  *(int4*)(bse + r*128 + sl*16) = A0;                                         \
  *(int4*)(bse + (64 + r)*128 + sl*16) = A1;                                  \
  *(int4*)(bse + ABYTES8 + r*128 + sl*16) = cvt8(F0, F1); }

#define GEMM8_KLOOP()                                                         \
  GLOAD(Aa0,Aa1,Af0,Af1, 0);                                                  \
  GLOAD(Ba0,Ba1,Bf0,Bf1, 1);                                                  \
  GLOAD(Ca0,Ca1,Cf0,Cf1, 2);                                                  \
  GLOAD(Da0,Da1,Df0,Df1, 3);                                                  \
  for (int it = 0; it < nit; it += 4) {                                       \
    GSTORE(lds, Aa0,Aa1,Af0,Af1);                                             \
    if (it + 4 < nit) GLOAD(Aa0,Aa1,Af0,Af1, it+4);                           \
    lds_barrier();                                                            \
    compute(lds);                                                             \
    GSTORE(lds + TILE8, Ba0,Ba1,Bf0,Bf1);                                     \
    if (it + 5 < nit) GLOAD(Ba0,Ba1,Bf0,Bf1, it+5);                           \
    lds_barrier();                                                            \
    compute(lds + TILE8);                                                     \
    GSTORE(lds, Ca0,Ca1,Cf0,Cf1);                                             \
    if (it + 6 < nit) GLOAD(Ca0,Ca1,Cf0,Cf1, it+6);                           \
    lds_barrier();                                                            \
    compute(lds);                                                             \
    GSTORE(lds + TILE8, Da0,Da1,Df0,Df1);                                     \
    if (it + 7 < nit) GLOAD(Da0,Da1,Df0,Df1, it+7);                           \
    lds_barrier();                                                            \
    compute(lds + TILE8);                                                     \
  }

#define GEMM8_PREAMBLE()                                                      \
  const int w = t >> 6, l = t & 63;                                           \
  const int wm = (w>>1)*32, wn = (w&1)*32;                                    \
  float4v acc[2][2];                                                          \
  _Pragma("unroll")                                                           \
  for (int m=0;m<2;++m)                                                       \
    _Pragma("unroll")                                                         \
    for (int n=0;n<2;++n) acc[m][n] = (float4v){0.f,0.f,0.f,0.f};             \
  const int r = t >> 3, sl = t & 7;                                           \
  const int gc = sl ^ (r & 7);                                                \
  const int quad = l >> 4, lrow = l & 15;                                     \
  int4 Aa0, Aa1;  float4 Af0, Af1;                                            \
  int4 Ba0, Ba1;  float4 Bf0, Bf1;                                            \
  int4 Ca0, Ca1;  float4 Cf0, Cf1;                                            \
  int4 Da0, Da1;  float4 Df0, Df1;                                            \
  auto compute = [&](const char* base) {                                      \
    const char* ab = base;                                                    \
    const char* bb = base + ABYTES8;                                          \
    _Pragma("unroll")                                                         \
    for (int step=0; step<2; ++step) {                                        \
      int c = step*4 + quad;                                                  \
      short8 af[2], bf[2];                                                    \
      _Pragma("unroll")                                                       \
      for (int m=0;m<2;++m) {                                                 \
        int Rw = wm + m*16 + lrow;                                            \
        af[m] = *(const short8*)(ab + Rw*128 + ((c ^ (Rw & 7))*16));          \
      }                                                                       \
      _Pragma("unroll")                                                       \
      for (int n=0;n<2;++n) {                                                 \
        int Rw = wn + n*16 + lrow;                                            \
        bf[n] = *(const short8*)(bb + Rw*128 + ((c ^ (Rw & 7))*16));          \
      }                                                                       \
      _Pragma("unroll")                                                       \
      for (int m=0;m<2;++m)                                                   \
        _Pragma("unroll")                                                     \
        for (int n=0;n<2;++n)                                                 \
          acc[m][n] = __builtin_amdgcn_mfma_f32_16x16x32_bf16(af[m], bf[n], acc[m][n], 0, 0, 0); \
    }                                                                         \
  };

// ---- standard-epilogue 8-wave GEMM (B fp32 direct) ----
template<int ZK, int OUT_BF16, int RELU, int HAS_SRC, int HAS_BIAS>
__device__ __forceinline__ void gemm8_dev(char* lds, int t,
    const unsigned short* __restrict__ Az, int lda,
    const float* __restrict__ Bz32, int ldb,
    const float* __restrict__ bias,
    const float* __restrict__ src, int ldsrc,
    void* __restrict__ Cv, int ldc,
    int bm, int bn, int nit)
{
  GEMM8_PREAMBLE();
  GEMM8_KLOOP();
  #pragma unroll
  for (int m=0;m<2;++m)
    #pragma unroll
    for (int n=0;n<2;++n)
      #pragma unroll
      for (int rg=0;rg<4;++rg) {
        int row = bm + wm + m*16 + quad*4 + rg;
        int col = bn + wn + n*16 + lrow;
        float vv = acc[m][n][rg];
        if (ZK) {
          atomicAdd(&((float*)Cv)[(size_t)row*ldc + col], vv);
        } else {
          if (HAS_BIAS) vv += bias[col];
          if (HAS_SRC)  vv += src[(size_t)row*ldsrc + col];
          if (RELU) vv = fmaxf(vv, 0.f);
          if (OUT_BF16) ((unsigned short*)Cv)[(size_t)row*ldc + col] = f2bu(vv);
          else          ((float*)Cv)[(size_t)row*ldc + col] = vv;
        }
      }
}

// ---- QKV-scatter 8-wave GEMM ----
__device__ __forceinline__ void gemm8_qkv_dev(char* lds, int t,
    const unsigned short* __restrict__ Az, int lda,
    const float* __restrict__ Bz32, int ldb,
    const float* __restrict__ bq, const float* __restrict__ bk,
    const float* __restrict__ bv,
    unsigned short* __restrict__ Qh, unsigned short* __restrict__ Kh,
    unsigned short* __restrict__ Vt,
    int bm, int bn, int nit)
{
  GEMM8_PREAMBLE();
  GEMM8_KLOOP();
  #pragma unroll
  for (int m=0;m<2;++m)
    #pragma unroll
    for (int n=0;n<2;++n)
      #pragma unroll
      for (int rg=0;rg<4;++rg) {
        int row = bm + wm + m*16 + quad*4 + rg;
        int col = bn + wn + n*16 + lrow;
        int part = col >> 10, hh = (col >> 7) & 7, d = col & 127;
        const float* bp = (part==0) ? bq : (part==1) ? bk : bv;
        float vv = acc[m][n][rg] + bp[col & 1023];
        unsigned short o = f2bu(vv);
        if (part == 0)      Qh[((size_t)hh*LL + row)*DKK + d] = o;
        else if (part == 1) Kh[(((size_t)hh*16 + (d>>3))*KLD + row)*8 + (d&7)] = o;
        else                Vt[(((size_t)hh*64 + (row>>3))*128 + d)*8 + (row&7)] = o;
      }
}

// ---- LayerNorm over one 1024-row with 512 threads (float2/thread) ----
__device__ __forceinline__ void ln_dev(char* lds, int t,
    const float* __restrict__ xr, const float* __restrict__ g,
    const float* __restrict__ b, unsigned short* __restrict__ yr,
    float* __restrict__ xw, const float* __restrict__ b2)
{
  const float2 xv = ((const float2*)xr)[t];
  float s = xv.x + xv.y, ss = xv.x*xv.x + xv.y*xv.y;
  #pragma unroll
  for (int off = 32; off >= 1; off >>= 1) {
    s += __shfl_xor(s, off); ss += __shfl_xor(ss, off);
  }
  float* red = (float*)lds;
  __syncthreads();
  if ((t & 63) == 0) { red[t >> 6] = s; red[8 + (t >> 6)] = ss; }
  __syncthreads();
  float S = 0.f, SS = 0.f;
  #pragma unroll
  for (int k2 = 0; k2 < 8; ++k2) { S += red[k2]; SS += red[8 + k2]; }
  float mean = S * (1.0f/DD);
  float var  = SS * (1.0f/DD) - mean*mean;
  float inv  = rsqrtf(var + 1e-5f);
  float2 gv = ((const float2*)g)[t], bv = ((const float2*)b)[t];
  ushort2 ov;
  ov.x = f2bu((xv.x-mean)*inv*gv.x + bv.x);
  ov.y = f2bu((xv.y-mean)*inv*gv.y + bv.y);
  ((ushort2*)yr)[t] = ov;
  if (b2) {
    float2 b2v = ((const float2*)b2)[t];
    float2 nx; nx.x = xv.x + b2v.x; nx.y = xv.y + b2v.y;
    ((float2*)xw)[t] = nx;
  }
  __syncthreads();
}

// ======== fused attention unit (v4 math, verbatim): 512 thr / 8 waves =======
#define A3_QROWB 272
#define A3_PROWB 1040
#define A3_SROWD 584
#define A3_O2ROW 132
#define A3_OFF_P   2176
#define A3_OFF_S   10496
#define A3_OFF_PW  29184
#define A3_OFF_PF1 30848
#define A3_OFF_PF2 30976
#define A3_OFF_SI  31104
#define A3_OFF_O2  31136

__device__ __forceinline__ void attn_dev(char* lds, int t, int unit,
    const unsigned short* __restrict__ Qh, const unsigned short* __restrict__ Kh,
    const unsigned short* __restrict__ Vt,
    const float* __restrict__ qcr, const float* __restrict__ cqr,
    const float* __restrict__ qtr, const float* __restrict__ tqr,
    const int* __restrict__ ct, const int* __restrict__ pred,
    const int* __restrict__ mask,
    const float* __restrict__ embv, const float* __restrict__ lqc_v,
    const float* __restrict__ lcq_v, const float* __restrict__ lqt_v,
    const float* __restrict__ ltq_v,
    unsigned short* __restrict__ obuf)
{
  const int w = t >> 6, l = t & 63, quad = l >> 4, lrow = l & 15;
  const int i0 = (unit & 63) * 8, h = unit >> 6;

  // zero pws/pf/sinv region (488 floats)
  for (int k2 = t; k2 < 488; k2 += 512) ((float*)(lds + A3_OFF_PW))[k2] = 0.f;

  // stage Q tile [8][128]
  if (t < 128) {
    int qr = t >> 4, qc = t & 15;
    *(int4*)(lds + qr*A3_QROWB + qc*16) =
        *(const int4*)(Qh + ((size_t)h*LL + i0 + qr)*DKK + qc*8);
  }
  lds_barrier();    // barrier 1: Qt + zeroed pws visible

  // ---- phase 1: S[8][576] = Q @ Kh^T, K fragments direct from global ----
  {
    const unsigned short* Kc = Kh + (size_t)h*16*KLD*8;
    short8 af0 = *(const short8*)(lds + lrow*A3_QROWB + (quad     )*16);
    short8 af1 = *(const short8*)(lds + lrow*A3_QROWB + (quad +  4)*16);
    short8 af2 = *(const short8*)(lds + lrow*A3_QROWB + (quad +  8)*16);
    short8 af3 = *(const short8*)(lds + lrow*A3_QROWB + (quad + 12)*16);
    #pragma unroll
    for (int s = w; s < 36; s += 8) {
      float4v acc = (float4v){0.f,0.f,0.f,0.f};
      int krow = s*16 + lrow;
      short8 bf0 = *(const short8*)(Kc + ((size_t)(quad     )*KLD + krow)*8);
      short8 bf1 = *(const short8*)(Kc + ((size_t)(quad +  4)*KLD + krow)*8);
      short8 bf2 = *(const short8*)(Kc + ((size_t)(quad +  8)*KLD + krow)*8);
      short8 bf3 = *(const short8*)(Kc + ((size_t)(quad + 12)*KLD + krow)*8);
      acc = __builtin_amdgcn_mfma_f32_16x16x32_bf16(af0, bf0, acc, 0, 0, 0);
      acc = __builtin_amdgcn_mfma_f32_16x16x32_bf16(af1, bf1, acc, 0, 0, 0);
      acc = __builtin_amdgcn_mfma_f32_16x16x32_bf16(af2, bf2, acc, 0, 0, 0);
      acc = __builtin_amdgcn_mfma_f32_16x16x32_bf16(af3, bf3, acc, 0, 0, 0);
      if (quad < 2) {
        #pragma unroll
        for (int rg = 0; rg < 4; ++rg)
          ((float*)(lds + A3_OFF_S))[(quad*4 + rg)*A3_SROWD + s*16 + lrow] = acc[rg];
      }
    }
  }
  lds_barrier();    // barrier 2: S visible

  // ---- phase 2: single-pass unnormalized softmax (64 lanes per row) ----
  const int row = t >> 6, l64 = t & 63;
  const int i = i0 + row;
  const float* Sp = (const float*)(lds + A3_OFF_S) + row*A3_SROWD;
  const int bse = (i0 < QQ) ? 562 : (i0 < QQ + CCC) ? 568 : 571;
  const float lq1a = Sp[bse], lq1b = Sp[bse+1], lq1c = Sp[bse+2];
  const float lq2a = Sp[565], lq2b = Sp[566], lq2c = Sp[567];

  float sum=0.f, f0=0.f, f1=0.f, f2=0.f, g0=0.f, g1=0.f, g2=0.f;
  float* pwsrow = (float*)(lds + A3_OFF_PW) + row*52;
  #pragma unroll
  for (int m = 0; m < 8; ++m) {
    int j = m*64 + l64;
    int predv = pred[i*LL + j];
    int maskv = mask[i*LL + j];
    float s = Sp[j] + Sp[512 + predv];
    float c0=0.f, c1=0.f, c2=0.f; int rt; int scat2 = 0;
    if (i0 < QQ) {
      if (j < QQ) { s += Sp[512]; rt = 0; }
      else if (j < QQ + CCC) {
        const float* r3 = qcr + ((size_t)i*CCC + (j - QQ))*3;
        c0 = r3[0]; c1 = r3[1]; c2 = r3[2];
        s += c0*lq1a + c1*lq1b + c2*lq1c; rt = 1;
      } else {
        const float* r3 = qtr + ((size_t)i*TTT + (j - QQ - CCC))*3;
        c0 = r3[0]; c1 = r3[1]; c2 = r3[2];
        s += c0*lq2a + c1*lq2b + c2*lq2c; rt = 2;
      }
    } else {
      if (j < QQ) {
        const float* r3 = (i < QQ + CCC) ? cqr + ((size_t)(i - QQ)*QQ + j)*3
                                         : tqr + ((size_t)(i - QQ - CCC)*QQ + j)*3;
        c0 = r3[0]; c1 = r3[1]; c2 = r3[2];
        s += c0*lq1a + c1*lq1b + c2*lq1c; rt = 1;
      } else {
        scat2 = ct[(i - QQ)*(CCC + TTT) + (j - QQ)];
        s += Sp[512 + scat2]; rt = 0;
      }
    }
    s *= 0.08838834764831845f;
    float e = (maskv == 0) ? 0.f : __expf(s);
    sum += e;
    *(unsigned short*)(lds + A3_OFF_P + row*A3_PROWB + j*2) = f2bu(e);
    atomicAdd(pwsrow + predv, e);
    if (rt == 0)      atomicAdd(pwsrow + scat2, e);
    else if (rt == 1) { f0 += e*c0; f1 += e*c1; f2 += e*c2; }
    else              { g0 += e*c0; g1 += e*c1; g2 += e*c2; }
  }
  #pragma unroll
  for (int off = 32; off >= 1; off >>= 1) {
    sum += __shfl_xor(sum, off);
    f0 += __shfl_xor(f0, off); f1 += __shfl_xor(f1, off); f2 += __shfl_xor(f2, off);
    g0 += __shfl_xor(g0, off); g1 += __shfl_xor(g1, off); g2 += __shfl_xor(g2, off);
  }
  if (l64 == 0) {
    float* pf1 = (float*)(lds + A3_OFF_PF1) + row*4;
    float* pf2 = (float*)(lds + A3_OFF_PF2) + row*4;
    pf1[0] = f0; pf1[1] = f1; pf1[2] = f2;
    pf2[0] = g0; pf2[1] = g1; pf2[2] = g2;
    ((float*)(lds + A3_OFF_SI))[row] = 1.0f / sum;
  }
  lds_barrier();    // barrier 3: P/pws/pf/sinv visible; S reads done

  // ---- o2term: o2s[row][d] = pws@embv + pf@tables (f32), 2 floats/thread ----
  {
    int orow = t >> 6, d0 = (t & 63)*2;
    const float* pwsr = (const float*)(lds + A3_OFF_PW) + orow*52;
    float a0=0.f, a1=0.f;
    #pragma unroll 5
    for (int rr = 0; rr < RR; ++rr) {
      float pv = pwsr[rr];
      float2 ev = *(const float2*)(embv + rr*DKK + d0);
      a0 += pv*ev.x; a1 += pv*ev.y;
    }
    const float* tab1 = (i0 < QQ) ? lqc_v : (i0 < QQ + CCC) ? lcq_v : ltq_v;
    const float* pf1 = (const float*)(lds + A3_OFF_PF1) + orow*4;
    float2 t0 = *(const float2*)(tab1 + d0);
    float2 t1 = *(const float2*)(tab1 + DKK + d0);
    float2 t2 = *(const float2*)(tab1 + 2*DKK + d0);
    a0 += pf1[0]*t0.x + pf1[1]*t1.x + pf1[2]*t2.x;
    a1 += pf1[0]*t0.y + pf1[1]*t1.y + pf1[2]*t2.y;
    if (i0 < QQ) {
      const float* pf2 = (const float*)(lds + A3_OFF_PF2) + orow*4;
      float2 u0 = *(const float2*)(lqt_v + d0);
      float2 u1 = *(const float2*)(lqt_v + DKK + d0);
      float2 u2 = *(const float2*)(lqt_v + 2*DKK + d0);
      a0 += pf2[0]*u0.x + pf2[1]*u1.x + pf2[2]*u2.x;
      a1 += pf2[0]*u0.y + pf2[1]*u1.y + pf2[2]*u2.y;
    }
    float2 av; av.x=a0; av.y=a1;
    *(float2*)((float*)(lds + A3_OFF_O2) + orow*A3_O2ROW + d0) = av;
  }
  lds_barrier();    // barrier 4: o2s visible

  // ---- phase 3: O[8][128] = E @ V^T; wave w owns d-cols [w*16, w*16+16) ----
  float4v oacc = (float4v){0.f,0.f,0.f,0.f};
  {
    const unsigned short* Vc = Vt + (size_t)h*64*128*8;
    #pragma unroll
    for (int it = 0; it < 8; ++it) {
      #pragma unroll
      for (int kk = 0; kk < 2; ++kk) {
        int c = kk*4 + quad;
        short8 pa = *(const short8*)(lds + A3_OFF_P + lrow*A3_PROWB + it*128 + c*16);
        short8 vf = *(const short8*)(Vc + (((size_t)(it*8 + c))*128 + w*16 + lrow)*8);
        oacc = __builtin_amdgcn_mfma_f32_16x16x32_bf16(pa, vf, oacc, 0, 0, 0);
      }
    }
  }

  // ---- epilogue: (oacc + o2s) * sinv -> obuf bf16 ----
  if (quad < 2) {
    const float* o2s = (const float*)(lds + A3_OFF_O2);
    const float* sinv = (const float*)(lds + A3_OFF_SI);
    int d = w*16 + lrow;
    #pragma unroll
    for (int rg = 0; rg < 4; ++rg) {
      int rw = quad*4 + rg;
      float val = (oacc[rg] + o2s[rw*A3_O2ROW + d]) * sinv[rw];
      obuf[(size_t)(i0 + rw)*DD + h*DKK + d] = f2bu(val);
    }
  }
  lds_barrier();    // protect LDS reads from next unit's zeroing
}

// ======== persistent mega-kernel: all 7 phases, 6 grid barriers ========
__global__ __launch_bounds__(512) void encoder_mega(
    const float* __restrict__ x,
    const float* __restrict__ qcr, const float* __restrict__ cqr,
    const float* __restrict__ qtr, const float* __restrict__ tqr,
    const int* __restrict__ ct, const int* __restrict__ pred,
    const int* __restrict__ mask,
    const float* __restrict__ embk, const float* __restrict__ embv,
    const float* __restrict__ lqc_k, const float* __restrict__ lqc_v,
    const float* __restrict__ lcq_k, const float* __restrict__ lcq_v,
    const float* __restrict__ lqt_k, const float* __restrict__ lqt_v,
    const float* __restrict__ ltq_k, const float* __restrict__ ltq_v,
    const float* __restrict__ Wq, const float* __restrict__ bq,
    const float* __restrict__ Wk, const float* __restrict__ bk,
    const float* __restrict__ Wv, const float* __restrict__ bv,
    const float* __restrict__ Wo, const float* __restrict__ bo,
    const float* __restrict__ ln1_g, const float* __restrict__ ln1_b,
    const float* __restrict__ ln2_g, const float* __restrict__ ln2_b,
    const float* __restrict__ W1, const float* __restrict__ b1,
    const float* __restrict__ W2, const float* __restrict__ b2,
    unsigned short* __restrict__ ybuf, unsigned short* __restrict__ obuf,
    unsigned short* __restrict__ Qh, unsigned short* __restrict__ Kh,
    unsigned short* __restrict__ Vt, unsigned short* __restrict__ hidden,
    float* __restrict__ out, unsigned* __restrict__ bar)
{
  __shared__ __align__(16) char lds[2*TILE8];
  const int bid = blockIdx.x, t = threadIdx.x;

  // ---- P0: LN1 (2 rows/block) + kprep (Kh rows 512..575) ----
  #pragma unroll
  for (int r2 = 0; r2 < 2; ++r2) {
    int row = bid + r2*256;
    ln_dev(lds, t, x + (size_t)row*DD, ln1_g, ln1_b,
           ybuf + (size_t)row*DD, nullptr, nullptr);
  }
  if (t < 256) {
    int gg = bid*256 + t;     // 256 blocks * 256 = 65536 = 8*64*128
    int d = gg & 127, rr = (gg >> 7) & 63, hh = gg >> 13;
    float v = 0.f;
    if (rr < 50) v = embk[rr*128 + d];
    else if (rr < 62) {
      int u = rr - 50; int tb = u/3, f = u - tb*3;
      const float* tab = (tb==0) ? lqc_k : (tb==1) ? lqt_k : (tb==2) ? lcq_k : ltq_k;
      v = tab[f*128 + d];
    }
    Kh[(((size_t)hh*16 + (d>>3))*KLD + 512 + rr)*8 + (d&7)] = f2bu(v);
  }
  gbar(bar + 0*16);

  // ---- P1: QKV GEMM (192 tiles of 128x64) with head scatter ----
  if (bid < 192) {
    int bx = bid % 48, by = bid / 48;
    int bm = by*128, bn = bx*64;
    int part0 = bn >> 10;
    const float* Bz32 = (part0==0 ? Wq : part0==1 ? Wk : Wv) + (size_t)(bn & 1023)*DD;
    gemm8_qkv_dev(lds, t, ybuf, DD, Bz32, DD, bq, bk, bv, Qh, Kh, Vt, bm, bn, 16);
  }
  gbar(bar + 1*16);

  // ---- P2: fused attention, 2 units/block (512 units total) ----
  #pragma unroll
  for (int uu = 0; uu < 2; ++uu)
    attn_dev(lds, t, bid + uu*256, Qh, Kh, Vt, qcr, cqr, qtr, tqr, ct, pred,
             mask, embv, lqc_v, lcq_v, lqt_v, ltq_v, obuf);
  gbar(bar + 2*16);

  // ---- P3: out-proj Wo + bo + residual(x) -> out (64 tiles) ----
  if (bid < 64) {
    int bm = (bid >> 4)*128, bn = (bid & 15)*64;
    gemm8_dev<0,0,0,1,1>(lds, t, obuf, DD, Wo + (size_t)bn*DD, DD,
                         bo, x, DD, out, DD, bm, bn, 16);
  }
  gbar(bar + 3*16);

  // ---- P4: LN2 -> ybuf bf16, out += b2 (2 rows/block) ----
  #pragma unroll
  for (int r2 = 0; r2 < 2; ++r2) {
    int row = bid + r2*256;
    ln_dev(lds, t, out + (size_t)row*DD, ln2_g, ln2_b,
           ybuf + (size_t)row*DD, out + (size_t)row*DD, b2);
  }
  gbar(bar + 4*16);

  // ---- P5: FFN1 relu -> hidden bf16 (256 tiles exactly) ----
  {
    int bm = (bid >> 6)*128, bn = (bid & 63)*64;
    gemm8_dev<0,1,1,0,1>(lds, t, ybuf, DD, W1 + (size_t)bn*DD, DD,
                         b1, nullptr, 0, hidden, FFF, bm, bn, 16);
  }
  gbar(bar + 5*16);

  // ---- P6: FFN2 split-K x4, atomicAdd -> out (256 blocks exactly) ----
  {
    int z = bid >> 6, tile = bid & 63;
    int bm = (tile >> 4)*128, bn = (tile & 15)*64;
    gemm8_dev<1,0,0,0,0>(lds, t, hidden + (size_t)z*1024, FFF,
                         W2 + (size_t)bn*FFF + (size_t)z*1024, FFF,
                         nullptr, nullptr, 0, out, DD, bm, bn, 16);
  }
}

// ---------------- launch ----------------
extern "C" void kernel_launch(void* const* d_in, const int* in_sizes, int n_in,
                              void* d_out, int out_size, void* d_ws, size_t ws_size,
                              hipStream_t stream)
{
  const float* x    = (const float*)d_in[0];
  const float* qcr  = (const float*)d_in[1];
  const float* cqr  = (const float*)d_in[2];
  const float* qtr  = (const float*)d_in[3];
  const float* tqr  = (const float*)d_in[4];
  const int*   ct   = (const int*)d_in[5];
  const int*   pred = (const int*)d_in[6];
  const int*   mask = (const int*)d_in[7];
  const float* embk = (const float*)d_in[8];
  const float* embv = (const float*)d_in[9];
  const float* lqc_k = (const float*)d_in[10];
  const float* lqc_v = (const float*)d_in[11];
  const float* lcq_k = (const float*)d_in[12];
  const float* lcq_v = (const float*)d_in[13];
  const float* lqt_k = (const float*)d_in[14];
  const float* lqt_v = (const float*)d_in[15];
  const float* ltq_k = (const float*)d_in[16];
  const float* ltq_v = (const float*)d_in[17];
  const float* Wq = (const float*)d_in[18]; const float* bq = (const float*)d_in[19];
  const float* Wk = (const float*)d_in[20]; const float* bk = (const float*)d_in[21];
  const float* Wv = (const float*)d_in[22]; const float* bv = (const float*)d_in[23];
  const float* Wo = (const float*)d_in[24]; const float* bo = (const float*)d_in[25];
  const float* ln1_g = (const float*)d_in[26]; const float* ln1_b = (const float*)d_in[27];
  const float* ln2_g = (const float*)d_in[28]; const float* ln2_b = (const float*)d_in[29];
  const float* W1 = (const float*)d_in[30]; const float* b1 = (const float*)d_in[31];
  const float* W2 = (const float*)d_in[32]; const float* b2 = (const float*)d_in[33];
  float* out = (float*)d_out;

  float* wsf = (float*)d_ws;
  float* S    = wsf;                          // FFN hidden region
  float* o2   = S + (size_t)HH*LL*SLD;        // layout stability (unused)
  unsigned short* ub = (unsigned short*)(o2 + (size_t)HH*LL*DKK);
  unsigned short* ybuf_b = ub;                        // [L,D]
  unsigned short* obuf_b = ybuf_b + LL*DD;            // [L,D]
  unsigned short* Qh     = obuf_b + LL*DD;            // [H][512][128]
  unsigned short* Kh     = Qh + (size_t)HH*LL*DKK;    // [H][16][576][8] slice-major
  unsigned short* Vt     = Kh + (size_t)HH*KLD*DKK;   // [H][64][128][8] slice-major
  unsigned short* hidden = (unsigned short*)S;        // [L][FFF] bf16
  unsigned* bar = (unsigned*)((char*)d_ws + ((ws_size - 1024) & ~(size_t)255));

  hipMemsetAsync(bar, 0, 1024, stream);
  encoder_mega<<<256, 512, 0, stream>>>(
      x, qcr, cqr, qtr, tqr, ct, pred, mask, embk, embv,
      lqc_k, lqc_v, lcq_k, lcq_v, lqt_k, lqt_v, ltq_k, ltq_v,
      Wq, bq, Wk, bk, Wv, bv, Wo, bo,
      ln1_g, ln1_b, ln2_g, ln2_b, W1, b1, W2, b2,
      ybuf_b, obuf_b, Qh, Kh, Vt, hidden, out, bar);
}

// Round 9
// 499.954 us; speedup vs baseline: 2.0868x; 1.5479x over previous
//
#include <hip/hip_runtime.h>
#include <hip/hip_bf16.h>

#define LL 512
#define DD 1024
#define HH 8
#define DKK 128
#define QQ 256
#define CCC 128
#define TTT 128
#define RR 50
#define FFF 4096
#define KLD 576          // Kh rows per head: 512 keys + 50 embk + 12 ltabs + 2 pad
#define SLD 576          // (kept for workspace layout arithmetic)

typedef __attribute__((ext_vector_type(8))) short short8;
typedef __attribute__((ext_vector_type(4))) float float4v;

__device__ __forceinline__ unsigned short f2bu(float f) {
  __hip_bfloat16 h = __float2bfloat16(f);
  unsigned short u; __builtin_memcpy(&u, &h, 2); return u;
}
__device__ __forceinline__ float b2f(unsigned short u) {
  unsigned int v = ((unsigned int)u) << 16;
  float f; __builtin_memcpy(&f, &v, 4); return f;
}
__device__ __forceinline__ int4 cvt8(float4 x, float4 y) {
  int4 o;
  o.x = (int)f2bu(x.x) | ((int)f2bu(x.y) << 16);
  o.y = (int)f2bu(x.z) | ((int)f2bu(x.w) << 16);
  o.z = (int)f2bu(y.x) | ((int)f2bu(y.y) << 16);
  o.w = (int)f2bu(y.z) | ((int)f2bu(y.w) << 16);
  return o;
}

// barrier draining only LDS (lgkmcnt(0)); global loads stay in flight.
__device__ __forceinline__ void lds_barrier() {
  __builtin_amdgcn_sched_barrier(0);
  __builtin_amdgcn_s_waitcnt(0xC07F);
  __builtin_amdgcn_s_barrier();
  __builtin_amdgcn_sched_barrier(0);
}

// ---- grid barrier: one-shot counter, all 256 blocks resident (1/CU) ----
// R7 lesson: ACQUIRE loads in the spin loop emit L2-invalidations every
// iteration (agent scope on non-coherent per-XCD L2s) -> continuous L2
// shootdown on every XCD while stragglers compute. Poll RELAXED (no cache
// maintenance), RELEASE on arrival (one L2 writeback), and a single
// acquire fence (__threadfence) at exit.
__device__ __forceinline__ void gbar(unsigned* slot) {
  __syncthreads();
  if (threadIdx.x == 0) {
    __hip_atomic_fetch_add(slot, 1u, __ATOMIC_RELEASE, __HIP_MEMORY_SCOPE_AGENT);
    while (__hip_atomic_load(slot, __ATOMIC_RELAXED, __HIP_MEMORY_SCOPE_AGENT) < 256u)
      __builtin_amdgcn_s_sleep(16);
  }
  __syncthreads();
  __threadfence();
}

// ---- K layout: slice-major [h][16 slices c][576 rows][8 elems] (bf16) ----
// ---- V layout: slice-major [h][64 slices c][128 d  ][8 elems] (bf16) ----

#define ABYTES8 (128*128)
#define TILE8 (ABYTES8 + 64*128)

// 8-wave GEMM staging: A bf16 2 int4/thread, B fp32 2 float4 -> cvt8.
#define GLOAD(A0,A1,F0,F1,itv) { int k0v = (itv) << 6;                        \
  A0 = *(const int4*)(Az + (size_t)(bm + r)*lda + k0v + gc*8);                \
  A1 = *(const int4*)(Az + (size_t)(bm + 64 + r)*lda + k0v + gc*8);           \
  F0 = *(const float4*)(Bz32 + (size_t)r*ldb + k0v + gc*8);                   \
  F1 = *(const float4*)(Bz32 + (size_t)r*ldb + k0v + gc*8 + 4); }

#define GSTORE(basep,A0,A1,F0,F1) { char* bse = (basep);                      \
  *(int4*)(bse + r*128 + sl*16) = A0;                                         \
  *(int4*)(bse + (64 + r)*128 + sl*16) = A1;                                  \
  *(int4*)(bse + ABYTES8 + r*128 + sl*16) = cvt8(F0, F1); }

#define GEMM8_KLOOP()                                                         \
  GLOAD(Aa0,Aa1,Af0,Af1, 0);                                                  \
  GLOAD(Ba0,Ba1,Bf0,Bf1, 1);                                                  \
  GLOAD(Ca0,Ca1,Cf0,Cf1, 2);                                                  \
  GLOAD(Da0,Da1,Df0,Df1, 3);                                                  \
  for (int it = 0; it < nit; it += 4) {                                       \
    GSTORE(lds, Aa0,Aa1,Af0,Af1);                                             \
    if (it + 4 < nit) GLOAD(Aa0,Aa1,Af0,Af1, it+4);                           \
    lds_barrier();                                                            \
    compute(lds);                                                             \
    GSTORE(lds + TILE8, Ba0,Ba1,Bf0,Bf1);                                     \
    if (it + 5 < nit) GLOAD(Ba0,Ba1,Bf0,Bf1, it+5);                           \
    lds_barrier();                                                            \
    compute(lds + TILE8);                                                     \
    GSTORE(lds, Ca0,Ca1,Cf0,Cf1);                                             \
    if (it + 6 < nit) GLOAD(Ca0,Ca1,Cf0,Cf1, it+6);                           \
    lds_barrier();                                                            \
    compute(lds);                                                             \
    GSTORE(lds + TILE8, Da0,Da1,Df0,Df1);                                     \
    if (it + 7 < nit) GLOAD(Da0,Da1,Df0,Df1, it+7);                           \
    lds_barrier();                                                            \
    compute(lds + TILE8);                                                     \
  }

#define GEMM8_PREAMBLE()                                                      \
  const int w = t >> 6, l = t & 63;                                           \
  const int wm = (w>>1)*32, wn = (w&1)*32;                                    \
  float4v acc[2][2];                                                          \
  _Pragma("unroll")                                                           \
  for (int m=0;m<2;++m)                                                       \
    _Pragma("unroll")                                                         \
    for (int n=0;n<2;++n) acc[m][n] = (float4v){0.f,0.f,0.f,0.f};             \
  const int r = t >> 3, sl = t & 7;                                           \
  const int gc = sl ^ (r & 7);                                                \
  const int quad = l >> 4, lrow = l & 15;                                     \
  int4 Aa0, Aa1;  float4 Af0, Af1;                                            \
  int4 Ba0, Ba1;  float4 Bf0, Bf1;                                            \
  int4 Ca0, Ca1;  float4 Cf0, Cf1;                                            \
  int4 Da0, Da1;  float4 Df0, Df1;                                            \
  auto compute = [&](const char* base) {                                      \
    const char* ab = base;                                                    \
    const char* bb = base + ABYTES8;                                          \
    _Pragma("unroll")                                                         \
    for (int step=0; step<2; ++step) {                                        \
      int c = step*4 + quad;                                                  \
      short8 af[2], bf[2];                                                    \
      _Pragma("unroll")                                                       \
      for (int m=0;m<2;++m) {                                                 \
        int Rw = wm + m*16 + lrow;                                            \
        af[m] = *(const short8*)(ab + Rw*128 + ((c ^ (Rw & 7))*16));          \
      }                                                                       \
      _Pragma("unroll")                                                       \
      for (int n=0;n<2;++n) {                                                 \
        int Rw = wn + n*16 + lrow;                                            \
        bf[n] = *(const short8*)(bb + Rw*128 + ((c ^ (Rw & 7))*16));          \
      }                                                                       \
      _Pragma("unroll")                                                       \
      for (int m=0;m<2;++m)                                                   \
        _Pragma("unroll")                                                     \
        for (int n=0;n<2;++n)                                                 \
          acc[m][n] = __builtin_amdgcn_mfma_f32_16x16x32_bf16(af[m], bf[n], acc[m][n], 0, 0, 0); \
    }                                                                         \
  };

// ---- standard-epilogue 8-wave GEMM (B fp32 direct) ----
template<int ZK, int OUT_BF16, int RELU, int HAS_SRC, int HAS_BIAS>
__device__ __forceinline__ void gemm8_dev(char* lds, int t,
    const unsigned short* __restrict__ Az, int lda,
    const float* __restrict__ Bz32, int ldb,
    const float* __restrict__ bias,
    const float* __restrict__ src, int ldsrc,
    void* __restrict__ Cv, int ldc,
    int bm, int bn, int nit)
{
  GEMM8_PREAMBLE();
  GEMM8_KLOOP();
  #pragma unroll
  for (int m=0;m<2;++m)
    #pragma unroll
    for (int n=0;n<2;++n)
      #pragma unroll
      for (int rg=0;rg<4;++rg) {
        int row = bm + wm + m*16 + quad*4 + rg;
        int col = bn + wn + n*16 + lrow;
        float vv = acc[m][n][rg];
        if (ZK) {
          atomicAdd(&((float*)Cv)[(size_t)row*ldc + col], vv);
        } else {
          if (HAS_BIAS) vv += bias[col];
          if (HAS_SRC)  vv += src[(size_t)row*ldsrc + col];
          if (RELU) vv = fmaxf(vv, 0.f);
          if (OUT_BF16) ((unsigned short*)Cv)[(size_t)row*ldc + col] = f2bu(vv);
          else          ((float*)Cv)[(size_t)row*ldc + col] = vv;
        }
      }
}

// ---- QKV-scatter 8-wave GEMM ----
__device__ __forceinline__ void gemm8_qkv_dev(char* lds, int t,
    const unsigned short* __restrict__ Az, int lda,
    const float* __restrict__ Bz32, int ldb,
    const float* __restrict__ bq, const float* __restrict__ bk,
    const float* __restrict__ bv,
    unsigned short* __restrict__ Qh, unsigned short* __restrict__ Kh,
    unsigned short* __restrict__ Vt,
    int bm, int bn, int nit)
{
  GEMM8_PREAMBLE();
  GEMM8_KLOOP();
  #pragma unroll
  for (int m=0;m<2;++m)
    #pragma unroll
    for (int n=0;n<2;++n)
      #pragma unroll
      for (int rg=0;rg<4;++rg) {
        int row = bm + wm + m*16 + quad*4 + rg;
        int col = bn + wn + n*16 + lrow;
        int part = col >> 10, hh = (col >> 7) & 7, d = col & 127;
        const float* bp = (part==0) ? bq : (part==1) ? bk : bv;
        float vv = acc[m][n][rg] + bp[col & 1023];
        unsigned short o = f2bu(vv);
        if (part == 0)      Qh[((size_t)hh*LL + row)*DKK + d] = o;
        else if (part == 1) Kh[(((size_t)hh*16 + (d>>3))*KLD + row)*8 + (d&7)] = o;
        else                Vt[(((size_t)hh*64 + (row>>3))*128 + d)*8 + (row&7)] = o;
      }
}

// ---- LayerNorm over one 1024-row with 512 threads (float2/thread) ----
__device__ __forceinline__ void ln_dev(char* lds, int t,
    const float* __restrict__ xr, const float* __restrict__ g,
    const float* __restrict__ b, unsigned short* __restrict__ yr,
    float* __restrict__ xw, const float* __restrict__ b2)
{
  const float2 xv = ((const float2*)xr)[t];
  float s = xv.x + xv.y, ss = xv.x*xv.x + xv.y*xv.y;
  #pragma unroll
  for (int off = 32; off >= 1; off >>= 1) {
    s += __shfl_xor(s, off); ss += __shfl_xor(ss, off);
  }
  float* red = (float*)lds;
  __syncthreads();
  if ((t & 63) == 0) { red[t >> 6] = s; red[8 + (t >> 6)] = ss; }
  __syncthreads();
  float S = 0.f, SS = 0.f;
  #pragma unroll
  for (int k2 = 0; k2 < 8; ++k2) { S += red[k2]; SS += red[8 + k2]; }
  float mean = S * (1.0f/DD);
  float var  = SS * (1.0f/DD) - mean*mean;
  float inv  = rsqrtf(var + 1e-5f);
  float2 gv = ((const float2*)g)[t], bv = ((const float2*)b)[t];
  ushort2 ov;
  ov.x = f2bu((xv.x-mean)*inv*gv.x + bv.x);
  ov.y = f2bu((xv.y-mean)*inv*gv.y + bv.y);
  ((ushort2*)yr)[t] = ov;
  if (b2) {
    float2 b2v = ((const float2*)b2)[t];
    float2 nx; nx.x = xv.x + b2v.x; nx.y = xv.y + b2v.y;
    ((float2*)xw)[t] = nx;
  }
  __syncthreads();
}

// ======== fused attention unit (v4 math, verbatim): 512 thr / 8 waves =======
#define A3_QROWB 272
#define A3_PROWB 1040
#define A3_SROWD 584
#define A3_O2ROW 132
#define A3_OFF_P   2176
#define A3_OFF_S   10496
#define A3_OFF_PW  29184
#define A3_OFF_PF1 30848
#define A3_OFF_PF2 30976
#define A3_OFF_SI  31104
#define A3_OFF_O2  31136

__device__ __forceinline__ void attn_dev(char* lds, int t, int unit,
    const unsigned short* __restrict__ Qh, const unsigned short* __restrict__ Kh,
    const unsigned short* __restrict__ Vt,
    const float* __restrict__ qcr, const float* __restrict__ cqr,
    const float* __restrict__ qtr, const float* __restrict__ tqr,
    const int* __restrict__ ct, const int* __restrict__ pred,
    const int* __restrict__ mask,
    const float* __restrict__ embv, const float* __restrict__ lqc_v,
    const float* __restrict__ lcq_v, const float* __restrict__ lqt_v,
    const float* __restrict__ ltq_v,
    unsigned short* __restrict__ obuf)
{
  const int w = t >> 6, l = t & 63, quad = l >> 4, lrow = l & 15;
  const int i0 = (unit & 63) * 8, h = unit >> 6;

  // zero pws/pf/sinv region (488 floats)
  for (int k2 = t; k2 < 488; k2 += 512) ((float*)(lds + A3_OFF_PW))[k2] = 0.f;

  // stage Q tile [8][128]
  if (t < 128) {
    int qr = t >> 4, qc = t & 15;
    *(int4*)(lds + qr*A3_QROWB + qc*16) =
        *(const int4*)(Qh + ((size_t)h*LL + i0 + qr)*DKK + qc*8);
  }
  lds_barrier();    // barrier 1: Qt + zeroed pws visible

  // ---- phase 1: S[8][576] = Q @ Kh^T, K fragments direct from global ----
  {
    const unsigned short* Kc = Kh + (size_t)h*16*KLD*8;
    short8 af0 = *(const short8*)(lds + lrow*A3_QROWB + (quad     )*16);
    short8 af1 = *(const short8*)(lds + lrow*A3_QROWB + (quad +  4)*16);
    short8 af2 = *(const short8*)(lds + lrow*A3_QROWB + (quad +  8)*16);
    short8 af3 = *(const short8*)(lds + lrow*A3_QROWB + (quad + 12)*16);
    #pragma unroll
    for (int s = w; s < 36; s += 8) {
      float4v acc = (float4v){0.f,0.f,0.f,0.f};
      int krow = s*16 + lrow;
      short8 bf0 = *(const short8*)(Kc + ((size_t)(quad     )*KLD + krow)*8);
      short8 bf1 = *(const short8*)(Kc + ((size_t)(quad +  4)*KLD + krow)*8);
      short8 bf2 = *(const short8*)(Kc + ((size_t)(quad +  8)*KLD + krow)*8);
      short8 bf3 = *(const short8*)(Kc + ((size_t)(quad + 12)*KLD + krow)*8);
      acc = __builtin_amdgcn_mfma_f32_16x16x32_bf16(af0, bf0, acc, 0, 0, 0);
      acc = __builtin_amdgcn_mfma_f32_16x16x32_bf16(af1, bf1, acc, 0, 0, 0);
      acc = __builtin_amdgcn_mfma_f32_16x16x32_bf16(af2, bf2, acc, 0, 0, 0);
      acc = __builtin_amdgcn_mfma_f32_16x16x32_bf16(af3, bf3, acc, 0, 0, 0);
      if (quad < 2) {
        #pragma unroll
        for (int rg = 0; rg < 4; ++rg)
          ((float*)(lds + A3_OFF_S))[(quad*4 + rg)*A3_SROWD + s*16 + lrow] = acc[rg];
      }
    }
  }
  lds_barrier();    // barrier 2: S visible

  // ---- phase 2: single-pass unnormalized softmax (64 lanes per row) ----
  const int row = t >> 6, l64 = t & 63;
  const int i = i0 + row;
  const float* Sp = (const float*)(lds + A3_OFF_S) + row*A3_SROWD;
  const int bse = (i0 < QQ) ? 562 : (i0 < QQ + CCC) ? 568 : 571;
  const float lq1a = Sp[bse], lq1b = Sp[bse+1], lq1c = Sp[bse+2];
  const float lq2a = Sp[565], lq2b = Sp[566], lq2c = Sp[567];

  float sum=0.f, f0=0.f, f1=0.f, f2=0.f, g0=0.f, g1=0.f, g2=0.f;
  float* pwsrow = (float*)(lds + A3_OFF_PW) + row*52;
  #pragma unroll
  for (int m = 0; m < 8; ++m) {
    int j = m*64 + l64;
    int predv = pred[i*LL + j];
    int maskv = mask[i*LL + j];
    float s = Sp[j] + Sp[512 + predv];
    float c0=0.f, c1=0.f, c2=0.f; int rt; int scat2 = 0;
    if (i0 < QQ) {
      if (j < QQ) { s += Sp[512]; rt = 0; }
      else if (j < QQ + CCC) {
        const float* r3 = qcr + ((size_t)i*CCC + (j - QQ))*3;
        c0 = r3[0]; c1 = r3[1]; c2 = r3[2];
        s += c0*lq1a + c1*lq1b + c2*lq1c; rt = 1;
      } else {
        const float* r3 = qtr + ((size_t)i*TTT + (j - QQ - CCC))*3;
        c0 = r3[0]; c1 = r3[1]; c2 = r3[2];
        s += c0*lq2a + c1*lq2b + c2*lq2c; rt = 2;
      }
    } else {
      if (j < QQ) {
        const float* r3 = (i < QQ + CCC) ? cqr + ((size_t)(i - QQ)*QQ + j)*3
                                         : tqr + ((size_t)(i - QQ - CCC)*QQ + j)*3;
        c0 = r3[0]; c1 = r3[1]; c2 = r3[2];
        s += c0*lq1a + c1*lq1b + c2*lq1c; rt = 1;
      } else {
        scat2 = ct[(i - QQ)*(CCC + TTT) + (j - QQ)];
        s += Sp[512 + scat2]; rt = 0;
      }
    }
    s *= 0.08838834764831845f;
    float e = (maskv == 0) ? 0.f : __expf(s);
    sum += e;
    *(unsigned short*)(lds + A3_OFF_P + row*A3_PROWB + j*2) = f2bu(e);
    atomicAdd(pwsrow + predv, e);
    if (rt == 0)      atomicAdd(pwsrow + scat2, e);
    else if (rt == 1) { f0 += e*c0; f1 += e*c1; f2 += e*c2; }
    else              { g0 += e*c0; g1 += e*c1; g2 += e*c2; }
  }
  #pragma unroll
  for (int off = 32; off >= 1; off >>= 1) {
    sum += __shfl_xor(sum, off);
    f0 += __shfl_xor(f0, off); f1 += __shfl_xor(f1, off); f2 += __shfl_xor(f2, off);
    g0 += __shfl_xor(g0, off); g1 += __shfl_xor(g1, off); g2 += __shfl_xor(g2, off);
  }
  if (l64 == 0) {
    float* pf1 = (float*)(lds + A3_OFF_PF1) + row*4;
    float* pf2 = (float*)(lds + A3_OFF_PF2) + row*4;
    pf1[0] = f0; pf1[1] = f1; pf1[2] = f2;
    pf2[0] = g0; pf2[1] = g1; pf2[2] = g2;
    ((float*)(lds + A3_OFF_SI))[row] = 1.0f / sum;
  }
  lds_barrier();    // barrier 3: P/pws/pf/sinv visible; S reads done

  // ---- o2term: o2s[row][d] = pws@embv + pf@tables (f32), 2 floats/thread ----
  {
    int orow = t >> 6, d0 = (t & 63)*2;
    const float* pwsr = (const float*)(lds + A3_OFF_PW) + orow*52;
    float a0=0.f, a1=0.f;
    #pragma unroll 5
    for (int rr = 0; rr < RR; ++rr) {
      float pv = pwsr[rr];
      float2 ev = *(const float2*)(embv + rr*DKK + d0);
      a0 += pv*ev.x; a1 += pv*ev.y;
    }
    const float* tab1 = (i0 < QQ) ? lqc_v : (i0 < QQ + CCC) ? lcq_v : ltq_v;
    const float* pf1 = (const float*)(lds + A3_OFF_PF1) + orow*4;
    float2 t0 = *(const float2*)(tab1 + d0);
    float2 t1 = *(const float2*)(tab1 + DKK + d0);
    float2 t2 = *(const float2*)(tab1 + 2*DKK + d0);
    a0 += pf1[0]*t0.x + pf1[1]*t1.x + pf1[2]*t2.x;
    a1 += pf1[0]*t0.y + pf1[1]*t1.y + pf1[2]*t2.y;
    if (i0 < QQ) {
      const float* pf2 = (const float*)(lds + A3_OFF_PF2) + orow*4;
      float2 u0 = *(const float2*)(lqt_v + d0);
      float2 u1 = *(const float2*)(lqt_v + DKK + d0);
      float2 u2 = *(const float2*)(lqt_v + 2*DKK + d0);
      a0 += pf2[0]*u0.x + pf2[1]*u1.x + pf2[2]*u2.x;
      a1 += pf2[0]*u0.y + pf2[1]*u1.y + pf2[2]*u2.y;
    }
    float2 av; av.x=a0; av.y=a1;
    *(float2*)((float*)(lds + A3_OFF_O2) + orow*A3_O2ROW + d0) = av;
  }
  lds_barrier();    // barrier 4: o2s visible

  // ---- phase 3: O[8][128] = E @ V^T; wave w owns d-cols [w*16, w*16+16) ----
  float4v oacc = (float4v){0.f,0.f,0.f,0.f};
  {
    const unsigned short* Vc = Vt + (size_t)h*64*128*8;
    #pragma unroll
    for (int it = 0; it < 8; ++it) {
      #pragma unroll
      for (int kk = 0; kk < 2; ++kk) {
        int c = kk*4 + quad;
        short8 pa = *(const short8*)(lds + A3_OFF_P + lrow*A3_PROWB + it*128 + c*16);
        short8 vf = *(const short8*)(Vc + (((size_t)(it*8 + c))*128 + w*16 + lrow)*8);
        oacc = __builtin_amdgcn_mfma_f32_16x16x32_bf16(pa, vf, oacc, 0, 0, 0);
      }
    }
  }

  // ---- epilogue: (oacc + o2s) * sinv -> obuf bf16 ----
  if (quad < 2) {
    const float* o2s = (const float*)(lds + A3_OFF_O2);
    const float* sinv = (const float*)(lds + A3_OFF_SI);
    int d = w*16 + lrow;
    #pragma unroll
    for (int rg = 0; rg < 4; ++rg) {
      int rw = quad*4 + rg;
      float val = (oacc[rg] + o2s[rw*A3_O2ROW + d]) * sinv[rw];
      obuf[(size_t)(i0 + rw)*DD + h*DKK + d] = f2bu(val);
    }
  }
  lds_barrier();    // protect LDS reads from next unit's zeroing
}

// ======== persistent mega-kernel: all 7 phases, 6 grid barriers ========
__global__ __launch_bounds__(512) void encoder_mega(
    const float* __restrict__ x,
    const float* __restrict__ qcr, const float* __restrict__ cqr,
    const float* __restrict__ qtr, const float* __restrict__ tqr,
    const int* __restrict__ ct, const int* __restrict__ pred,
    const int* __restrict__ mask,
    const float* __restrict__ embk, const float* __restrict__ embv,
    const float* __restrict__ lqc_k, const float* __restrict__ lqc_v,
    const float* __restrict__ lcq_k, const float* __restrict__ lcq_v,
    const float* __restrict__ lqt_k, const float* __restrict__ lqt_v,
    const float* __restrict__ ltq_k, const float* __restrict__ ltq_v,
    const float* __restrict__ Wq, const float* __restrict__ bq,
    const float* __restrict__ Wk, const float* __restrict__ bk,
    const float* __restrict__ Wv, const float* __restrict__ bv,
    const float* __restrict__ Wo, const float* __restrict__ bo,
    const float* __restrict__ ln1_g, const float* __restrict__ ln1_b,
    const float* __restrict__ ln2_g, const float* __restrict__ ln2_b,
    const float* __restrict__ W1, const float* __restrict__ b1,
    const float* __restrict__ W2, const float* __restrict__ b2,
    unsigned short* __restrict__ ybuf, unsigned short* __restrict__ obuf,
    unsigned short* __restrict__ Qh, unsigned short* __restrict__ Kh,
    unsigned short* __restrict__ Vt, unsigned short* __restrict__ hidden,
    float* __restrict__ out, unsigned* __restrict__ bar)
{
  __shared__ __align__(16) char lds[2*TILE8];
  const int bid = blockIdx.x, t = threadIdx.x;

  // ---- P0: LN1 (2 rows/block) + kprep (Kh rows 512..575) ----
  #pragma unroll
  for (int r2 = 0; r2 < 2; ++r2) {
    int row = bid + r2*256;
    ln_dev(lds, t, x + (size_t)row*DD, ln1_g, ln1_b,
           ybuf + (size_t)row*DD, nullptr, nullptr);
  }
  if (t < 256) {
    int gg = bid*256 + t;     // 256 blocks * 256 = 65536 = 8*64*128
    int d = gg & 127, rr = (gg >> 7) & 63, hh = gg >> 13;
    float v = 0.f;
    if (rr < 50) v = embk[rr*128 + d];
    else if (rr < 62) {
      int u = rr - 50; int tb = u/3, f = u - tb*3;
      const float* tab = (tb==0) ? lqc_k : (tb==1) ? lqt_k : (tb==2) ? lcq_k : ltq_k;
      v = tab[f*128 + d];
    }
    Kh[(((size_t)hh*16 + (d>>3))*KLD + 512 + rr)*8 + (d&7)] = f2bu(v);
  }
  gbar(bar + 0*16);

  // ---- P1: QKV GEMM (192 tiles of 128x64) with head scatter ----
  if (bid < 192) {
    int bx = bid % 48, by = bid / 48;
    int bm = by*128, bn = bx*64;
    int part0 = bn >> 10;
    const float* Bz32 = (part0==0 ? Wq : part0==1 ? Wk : Wv) + (size_t)(bn & 1023)*DD;
    gemm8_qkv_dev(lds, t, ybuf, DD, Bz32, DD, bq, bk, bv, Qh, Kh, Vt, bm, bn, 16);
  }
  gbar(bar + 1*16);

  // ---- P2: fused attention, 2 units/block (512 units total) ----
  #pragma unroll
  for (int uu = 0; uu < 2; ++uu)
    attn_dev(lds, t, bid + uu*256, Qh, Kh, Vt, qcr, cqr, qtr, tqr, ct, pred,
             mask, embv, lqc_v, lcq_v, lqt_v, ltq_v, obuf);
  gbar(bar + 2*16);

  // ---- P3: out-proj Wo + bo + residual(x) -> out (64 tiles) ----
  if (bid < 64) {
    int bm = (bid >> 4)*128, bn = (bid & 15)*64;
    gemm8_dev<0,0,0,1,1>(lds, t, obuf, DD, Wo + (size_t)bn*DD, DD,
                         bo, x, DD, out, DD, bm, bn, 16);
  }
  gbar(bar + 3*16);

  // ---- P4: LN2 -> ybuf bf16, out += b2 (2 rows/block) ----
  #pragma unroll
  for (int r2 = 0; r2 < 2; ++r2) {
    int row = bid + r2*256;
    ln_dev(lds, t, out + (size_t)row*DD, ln2_g, ln2_b,
           ybuf + (size_t)row*DD, out + (size_t)row*DD, b2);
  }
  gbar(bar + 4*16);

  // ---- P5: FFN1 relu -> hidden bf16 (256 tiles exactly) ----
  {
    int bm = (bid >> 6)*128, bn = (bid & 63)*64;
    gemm8_dev<0,1,1,0,1>(lds, t, ybuf, DD, W1 + (size_t)bn*DD, DD,
                         b1, nullptr, 0, hidden, FFF, bm, bn, 16);
  }
  gbar(bar + 5*16);

  // ---- P6: FFN2 split-K x4, atomicAdd -> out (256 blocks exactly) ----
  {
    int z = bid >> 6, tile = bid & 63;
    int bm = (tile >> 4)*128, bn = (tile & 15)*64;
    gemm8_dev<1,0,0,0,0>(lds, t, hidden + (size_t)z*1024, FFF,
                         W2 + (size_t)bn*FFF + (size_t)z*1024, FFF,
                         nullptr, nullptr, 0, out, DD, bm, bn, 16);
  }
}

// ---------------- launch ----------------
extern "C" void kernel_launch(void* const* d_in, const int* in_sizes, int n_in,
                              void* d_out, int out_size, void* d_ws, size_t ws_size,
                              hipStream_t stream)
{
  const float* x    = (const float*)d_in[0];
  const float* qcr  = (const float*)d_in[1];
  const float* cqr  = (const float*)d_in[2];
  const float* qtr  = (const float*)d_in[3];
  const float* tqr  = (const float*)d_in[4];
  const int*   ct   = (const int*)d_in[5];
  const int*   pred = (const int*)d_in[6];
  const int*   mask = (const int*)d_in[7];
  const float* embk = (const float*)d_in[8];
  const float* embv = (const float*)d_in[9];
  const float* lqc_k = (const float*)d_in[10];
  const float* lqc_v = (const float*)d_in[11];
  const float* lcq_k = (const float*)d_in[12];
  const float* lcq_v = (const float*)d_in[13];
  const float* lqt_k = (const float*)d_in[14];
  const float* lqt_v = (const float*)d_in[15];
  const float* ltq_k = (const float*)d_in[16];
  const float* ltq_v = (const float*)d_in[17];
  const float* Wq = (const float*)d_in[18]; const float* bq = (const float*)d_in[19];
  const float* Wk = (const float*)d_in[20]; const float* bk = (const float*)d_in[21];
  const float* Wv = (const float*)d_in[22]; const float* bv = (const float*)d_in[23];
  const float* Wo = (const float*)d_in[24]; const float* bo = (const float*)d_in[25];
  const float* ln1_g = (const float*)d_in[26]; const float* ln1_b = (const float*)d_in[27];
  const float* ln2_g = (const float*)d_in[28]; const float* ln2_b = (const float*)d_in[29];
  const float* W1 = (const float*)d_in[30]; const float* b1 = (const float*)d_in[31];
  const float* W2 = (const float*)d_in[32]; const float* b2 = (const float*)d_in[33];
  float* out = (float*)d_out;

  float* wsf = (float*)d_ws;
  float* S    = wsf;                          // FFN hidden region
  float* o2   = S + (size_t)HH*LL*SLD;        // layout stability (unused)
  unsigned short* ub = (unsigned short*)(o2 + (size_t)HH*LL*DKK);
  unsigned short* ybuf_b = ub;                        // [L,D]
  unsigned short* obuf_b = ybuf_b + LL*DD;            // [L,D]
  unsigned short* Qh     = obuf_b + LL*DD;            // [H][512][128]
  unsigned short* Kh     = Qh + (size_t)HH*LL*DKK;    // [H][16][576][8] slice-major
  unsigned short* Vt     = Kh + (size_t)HH*KLD*DKK;   // [H][64][128][8] slice-major
  unsigned short* hidden = (unsigned short*)S;        // [L][FFF] bf16
  unsigned* bar = (unsigned*)((char*)d_ws + ((ws_size - 1024) & ~(size_t)255));

  hipMemsetAsync(bar, 0, 1024, stream);
  encoder_mega<<<256, 512, 0, stream>>>(
      x, qcr, cqr, qtr, tqr, ct, pred, mask, embk, embv,
      lqc_k, lqc_v, lcq_k, lcq_v, lqt_k, lqt_v, ltq_k, ltq_v,
      Wq, bq, Wk, bk, Wv, bv, Wo, bo,
      ln1_g, ln1_b, ln2_g, ln2_b, W1, b1, W2, b2,
      ybuf_b, obuf_b, Qh, Kh, Vt, hidden, out, bar);
}

// Round 10
// 228.638 us; speedup vs baseline: 4.5632x; 2.1867x over previous
//
#include <hip/hip_runtime.h>
#include <hip/hip_bf16.h>

#define LL 512
#define DD 1024
#define HH 8
#define DKK 128
#define QQ 256
#define CCC 128
#define TTT 128
#define RR 50
#define FFF 4096
#define KLD 576          // Kh rows per head: 512 keys + 50 embk + 12 ltabs + 2 pad
#define SLD 576          // (kept for workspace layout arithmetic)

typedef __attribute__((ext_vector_type(8))) short short8;
typedef __attribute__((ext_vector_type(4))) float float4v;

__device__ __forceinline__ unsigned short f2bu(float f) {
  __hip_bfloat16 h = __float2bfloat16(f);
  unsigned short u; __builtin_memcpy(&u, &h, 2); return u;
}
__device__ __forceinline__ float b2f(unsigned short u) {
  unsigned int v = ((unsigned int)u) << 16;
  float f; __builtin_memcpy(&f, &v, 4); return f;
}
__device__ __forceinline__ int4 cvt8(float4 x, float4 y) {
  int4 o;
  o.x = (int)f2bu(x.x) | ((int)f2bu(x.y) << 16);
  o.y = (int)f2bu(x.z) | ((int)f2bu(x.w) << 16);
  o.z = (int)f2bu(y.x) | ((int)f2bu(y.y) << 16);
  o.w = (int)f2bu(y.z) | ((int)f2bu(y.w) << 16);
  return o;
}

// barrier draining only LDS (lgkmcnt(0)); global loads stay in flight.
__device__ __forceinline__ void lds_barrier() {
  __builtin_amdgcn_sched_barrier(0);
  __builtin_amdgcn_s_waitcnt(0xC07F);
  __builtin_amdgcn_s_barrier();
  __builtin_amdgcn_sched_barrier(0);
}

// explicit-scalar load/store macros: no arrays, no pointer params -> no scratch.
#define LOADSET(A0,A1,B0,B1,F0,F1,F2,F3,itv) { int k0v = (itv) << 6;          \
  A0 = *(const int4*)(Az + (size_t)(bm + r)*lda + k0v + gc*8);                \
  A1 = *(const int4*)(Az + (size_t)(bm + 32 + r)*lda + k0v + gc*8);           \
  if constexpr (!CONVB) {                                                     \
    B0 = *(const int4*)(Bz16 + (size_t)(bnb + r)*ldb + k0v + gc*8);           \
    if constexpr (NB > 1)                                                     \
      B1 = *(const int4*)(Bz16 + (size_t)(bnb + 32 + r)*ldb + k0v + gc*8);    \
  } else {                                                                    \
    F0 = *(const float4*)(Bz32 + (size_t)(bnb + r)*ldb + k0v + gc*8);         \
    F1 = *(const float4*)(Bz32 + (size_t)(bnb + r)*ldb + k0v + gc*8 + 4);     \
    if constexpr (NB > 1) {                                                   \
      F2 = *(const float4*)(Bz32 + (size_t)(bnb + 32 + r)*ldb + k0v + gc*8);  \
      F3 = *(const float4*)(Bz32 + (size_t)(bnb + 32 + r)*ldb + k0v + gc*8 + 4); } } }

#define STORESET2(basep,A0,A1,B0,B1,F0,F1,F2,F3) {                            \
  char* bse = (basep);                                                        \
  *(int4*)(bse + r*128 + sl*16) = A0;                                         \
  *(int4*)(bse + (32 + r)*128 + sl*16) = A1;                                  \
  if constexpr (!CONVB) {                                                     \
    *(int4*)(bse + ABYTES + r*128 + sl*16) = B0;                              \
    if constexpr (NB > 1)                                                     \
      *(int4*)(bse + ABYTES + (32 + r)*128 + sl*16) = B1;                     \
  } else {                                                                    \
    *(int4*)(bse + ABYTES + r*128 + sl*16) = cvt8(F0, F1);                    \
    if constexpr (NB > 1)                                                     \
      *(int4*)(bse + ABYTES + (32 + r)*128 + sl*16) = cvt8(F2, F3); } }

// 8-wave (BM=128) variants: A = 2 int4/thread, B = 1 int4 (or 2 float4 cvt).
#define LOADSET8(A0,A1,B0,F0,F1,itv) { int k0v = (itv) << 6;                  \
  A0 = *(const int4*)(Az + (size_t)(bm + r)*lda + k0v + gc*8);                \
  A1 = *(const int4*)(Az + (size_t)(bm + 64 + r)*lda + k0v + gc*8);           \
  if constexpr (!CONVB) {                                                     \
    B0 = *(const int4*)(Bz16 + (size_t)(bnb + r)*ldb + k0v + gc*8);           \
  } else {                                                                    \
    F0 = *(const float4*)(Bz32 + (size_t)(bnb + r)*ldb + k0v + gc*8);         \
    F1 = *(const float4*)(Bz32 + (size_t)(bnb + r)*ldb + k0v + gc*8 + 4); } }

#define STORESET8(basep,A0,A1,B0,F0,F1) {                                     \
  char* bse = (basep);                                                        \
  *(int4*)(bse + r*128 + sl*16) = A0;                                         \
  *(int4*)(bse + (64 + r)*128 + sl*16) = A1;                                  \
  if constexpr (!CONVB) {                                                     \
    *(int4*)(bse + ABYTES + r*128 + sl*16) = B0;                              \
  } else {                                                                    \
    *(int4*)(bse + ABYTES + r*128 + sl*16) = cvt8(F0, F1); } }

// ---- K layout: slice-major [h][16 slices c][576 rows][8 elems] (bf16) ----
// ---- V layout: slice-major [h][64 slices c][128 d  ][8 elems] (bf16) ----

// ---------------- LayerNorm: fp32 in, bf16 out; + fused kprep ----------------
__global__ __launch_bounds__(256) void ln_bf16_kernel(const float* __restrict__ x,
    const float* __restrict__ g, const float* __restrict__ b,
    unsigned short* __restrict__ y,
    const float* __restrict__ embk,
    const float* __restrict__ lqc, const float* __restrict__ lqt,
    const float* __restrict__ lcq, const float* __restrict__ ltq,
    unsigned short* __restrict__ Kh)
{
  int row = blockIdx.x, t = threadIdx.x;
  const float4 xv = ((const float4*)(x + row*DD))[t];
  float s  = xv.x+xv.y+xv.z+xv.w;
  float ss = xv.x*xv.x+xv.y*xv.y+xv.z*xv.z+xv.w*xv.w;
  __shared__ float rs[256], rss[256];
  rs[t]=s; rss[t]=ss; __syncthreads();
  for (int st=128; st>0; st>>=1){ if (t<st){ rs[t]+=rs[t+st]; rss[t]+=rss[t+st]; } __syncthreads(); }
  float mean = rs[0] * (1.0f/DD);
  float var  = rss[0]*(1.0f/DD) - mean*mean;
  float inv  = rsqrtf(var + 1e-5f);
  float4 gv = ((const float4*)g)[t], bv = ((const float4*)b)[t];
  ushort4 ov;
  ov.x = f2bu((xv.x-mean)*inv*gv.x + bv.x);
  ov.y = f2bu((xv.y-mean)*inv*gv.y + bv.y);
  ov.z = f2bu((xv.z-mean)*inv*gv.z + bv.z);
  ov.w = f2bu((xv.w-mean)*inv*gv.w + bv.w);
  ((ushort4*)(y + row*DD))[t] = ov;
  // fused kprep: fill Kh rows 512..575 (first 256 blocks, 1 elem/thread)
  int gg = blockIdx.x*256 + t;
  if (gg < 8*64*128) {
    int d = gg & 127, rr = (gg >> 7) & 63, hh = gg >> 13;
    float v = 0.f;
    if (rr < 50) v = embk[rr*128 + d];
    else if (rr < 62) {
      int u = rr - 50; int tb = u/3, f = u - tb*3;
      const float* tab = (tb==0) ? lqc : (tb==1) ? lqt : (tb==2) ? lcq : ltq;
      v = tab[f*128 + d];
    }
    Kh[(((size_t)hh*16 + (d>>3))*KLD + 512 + rr)*8 + (d&7)] = f2bu(v);
  }
}

// ---------------- LayerNorm + out += b2 (split-K init) ----------------
__global__ __launch_bounds__(256) void ln_bf16_addb_kernel(float* __restrict__ x,
    const float* __restrict__ g, const float* __restrict__ b,
    const float* __restrict__ b2, unsigned short* __restrict__ y)
{
  int row = blockIdx.x, t = threadIdx.x;
  const float4 xv = ((const float4*)(x + row*DD))[t];
  float s  = xv.x+xv.y+xv.z+xv.w;
  float ss = xv.x*xv.x+xv.y*xv.y+xv.z*xv.z+xv.w*xv.w;
  __shared__ float rs[256], rss[256];
  rs[t]=s; rss[t]=ss; __syncthreads();
  for (int st=128; st>0; st>>=1){ if (t<st){ rs[t]+=rs[t+st]; rss[t]+=rss[t+st]; } __syncthreads(); }
  float mean = rs[0] * (1.0f/DD);
  float var  = rss[0]*(1.0f/DD) - mean*mean;
  float inv  = rsqrtf(var + 1e-5f);
  float4 gv = ((const float4*)g)[t], bv = ((const float4*)b)[t];
  ushort4 ov;
  ov.x = f2bu((xv.x-mean)*inv*gv.x + bv.x);
  ov.y = f2bu((xv.y-mean)*inv*gv.y + bv.y);
  ov.z = f2bu((xv.z-mean)*inv*gv.z + bv.z);
  ov.w = f2bu((xv.w-mean)*inv*gv.w + bv.w);
  ((ushort4*)(y + row*DD))[t] = ov;
  float4 b2v = ((const float4*)b2)[t];
  float4 nx; nx.x = xv.x+b2v.x; nx.y = xv.y+b2v.y; nx.z = xv.z+b2v.z; nx.w = xv.w+b2v.w;
  ((float4*)(x + row*DD))[t] = nx;
}

// ======== VGPR-staged pipelined bf16 MFMA GEMM; DEPTH = prefetch depth ======
template<int BN, int DEPTH, int CONVB, int ZK, int OUT_BF16, int RELU, int HAS_SRC, int HAS_BIAS>
__global__ __launch_bounds__(256) void gemm_pl(
    const unsigned short* __restrict__ A, int lda, size_t sAz,
    const void* __restrict__ Bv, int ldb, size_t sBz,
    const float* __restrict__ bias,
    const float* __restrict__ src, int ldsrc, size_t sSz,
    void* __restrict__ Cv, int ldc, size_t sCz,
    int K)
{
  constexpr int BM = 64;
  constexpr int WM = 32, WN = BN/2, FM = 2, FN = WN/16;
  constexpr int NB = BN/32;
  constexpr int ABYTES = BM*128, TILE = ABYTES + BN*128;
  __shared__ char lds[2*TILE];
  int t = threadIdx.x, w = t >> 6, l = t & 63;
  size_t z = blockIdx.z;
  const unsigned short* Az = A + z*sAz;
  const unsigned short* Bz16 = (const unsigned short*)Bv + (CONVB ? 0 : z*sBz);
  const float*          Bz32 = (const float*)Bv + (CONVB ? z*sBz : 0);
  int bm = blockIdx.y*BM, bn = blockIdx.x*BN;
  int bnb = bn;
  int wm = (w>>1)*WM, wn = (w&1)*WN;

  float4v acc[FM][FN];
  #pragma unroll
  for (int m=0;m<FM;++m)
    #pragma unroll
    for (int n=0;n<FN;++n) acc[m][n] = (float4v){0.f,0.f,0.f,0.f};

  int r = t >> 3, sl = t & 7;
  int gc = sl ^ (r & 7);
  int quad = l >> 4, lrow = l & 15;
  const int nit = K >> 6;   // DEPTH==2: nit even; DEPTH==4: nit % 4 == 0

  int4 Aa0, Aa1, Ab0, Ab1;  float4 Af0, Af1, Af2, Af3;
  int4 Ba0, Ba1, Bb0, Bb1;  float4 Bf0, Bf1, Bf2, Bf3;
  int4 Ca0, Ca1, Cb0, Cb1;  float4 Cf0, Cf1, Cf2, Cf3;
  int4 Da0, Da1, Db0, Db1;  float4 Df0, Df1, Df2, Df3;

  auto compute = [&](const char* base) {
    const char* ab = base;
    const char* bb = base + ABYTES;
    #pragma unroll
    for (int step=0; step<2; ++step) {
      int c = step*4 + quad;
      short8 af[FM], bf[FN];
      #pragma unroll
      for (int m=0;m<FM;++m) {
        int Rw = wm + m*16 + lrow;
        af[m] = *(const short8*)(ab + Rw*128 + ((c ^ (Rw & 7))*16));
      }
      #pragma unroll
      for (int n=0;n<FN;++n) {
        int Rw = wn + n*16 + lrow;
        bf[n] = *(const short8*)(bb + Rw*128 + ((c ^ (Rw & 7))*16));
      }
      #pragma unroll
      for (int m=0;m<FM;++m)
        #pragma unroll
        for (int n=0;n<FN;++n)
          acc[m][n] = __builtin_amdgcn_mfma_f32_16x16x32_bf16(af[m], bf[n], acc[m][n], 0, 0, 0);
    }
  };

  if constexpr (DEPTH == 2) {
    LOADSET(Aa0,Aa1,Ab0,Ab1,Af0,Af1,Af2,Af3, 0);
    LOADSET(Ba0,Ba1,Bb0,Bb1,Bf0,Bf1,Bf2,Bf3, 1);
    for (int it = 0; it < nit; it += 2) {
      STORESET2(lds, Aa0,Aa1,Ab0,Ab1,Af0,Af1,Af2,Af3);
      if (it + 2 < nit) LOADSET(Aa0,Aa1,Ab0,Ab1,Af0,Af1,Af2,Af3, it+2);
      lds_barrier();
      compute(lds);
      STORESET2(lds + TILE, Ba0,Ba1,Bb0,Bb1,Bf0,Bf1,Bf2,Bf3);
      if (it + 3 < nit) LOADSET(Ba0,Ba1,Bb0,Bb1,Bf0,Bf1,Bf2,Bf3, it+3);
      lds_barrier();
      compute(lds + TILE);
    }
  } else {
    LOADSET(Aa0,Aa1,Ab0,Ab1,Af0,Af1,Af2,Af3, 0);
    LOADSET(Ba0,Ba1,Bb0,Bb1,Bf0,Bf1,Bf2,Bf3, 1);
    LOADSET(Ca0,Ca1,Cb0,Cb1,Cf0,Cf1,Cf2,Cf3, 2);
    LOADSET(Da0,Da1,Db0,Db1,Df0,Df1,Df2,Df3, 3);
    for (int it = 0; it < nit; it += 4) {
      STORESET2(lds, Aa0,Aa1,Ab0,Ab1,Af0,Af1,Af2,Af3);
      if (it + 4 < nit) LOADSET(Aa0,Aa1,Ab0,Ab1,Af0,Af1,Af2,Af3, it+4);
      lds_barrier();
      compute(lds);
      STORESET2(lds + TILE, Ba0,Ba1,Bb0,Bb1,Bf0,Bf1,Bf2,Bf3);
      if (it + 5 < nit) LOADSET(Ba0,Ba1,Bb0,Bb1,Bf0,Bf1,Bf2,Bf3, it+5);
      lds_barrier();
      compute(lds + TILE);
      STORESET2(lds, Ca0,Ca1,Cb0,Cb1,Cf0,Cf1,Cf2,Cf3);
      if (it + 6 < nit) LOADSET(Ca0,Ca1,Cb0,Cb1,Cf0,Cf1,Cf2,Cf3, it+6);
      lds_barrier();
      compute(lds);
      STORESET2(lds + TILE, Da0,Da1,Db0,Db1,Df0,Df1,Df2,Df3);
      if (it + 7 < nit) LOADSET(Da0,Da1,Db0,Db1,Df0,Df1,Df2,Df3, it+7);
      lds_barrier();
      compute(lds + TILE);
    }
  }

  #pragma unroll
  for (int m=0;m<FM;++m)
    #pragma unroll
    for (int n=0;n<FN;++n)
      #pragma unroll
      for (int rg=0;rg<4;++rg) {
        int row = bm + wm + m*16 + quad*4 + rg;
        int col = bn + wn + n*16 + lrow;
        float vv = acc[m][n][rg];
        if (ZK) {
          atomicAdd(&((float*)Cv)[(size_t)row*ldc + col], vv);
        } else {
          if (HAS_BIAS) vv += bias[col];
          if (HAS_SRC)  vv += src[z*sSz + (size_t)row*ldsrc + col];
          if (RELU) vv = fmaxf(vv, 0.f);
          if (OUT_BF16) ((unsigned short*)Cv)[z*sCz + (size_t)row*ldc + col] = f2bu(vv);
          else          ((float*)Cv)[z*sCz + (size_t)row*ldc + col] = vv;
        }
      }
}

// ======== 8-wave BM=128 pipelined GEMM (512 thr, 4M x 2N waves, DEPTH 4) ====
template<int BN, int CONVB, int ZK, int OUT_BF16, int RELU, int HAS_SRC, int HAS_BIAS>
__global__ __launch_bounds__(512) void gemm_pl8(
    const unsigned short* __restrict__ A, int lda, size_t sAz,
    const void* __restrict__ Bv, int ldb, size_t sBz,
    const float* __restrict__ bias,
    const float* __restrict__ src, int ldsrc, size_t sSz,
    void* __restrict__ Cv, int ldc, size_t sCz,
    int K)
{
  constexpr int BM = 128;
  constexpr int FM = 2, FN = 2;
  constexpr int ABYTES = BM*128, TILE = ABYTES + BN*128;   // BN==64
  __shared__ char lds[2*TILE];
  int t = threadIdx.x, w = t >> 6, l = t & 63;
  size_t z = blockIdx.z;
  const unsigned short* Az = A + z*sAz;
  const unsigned short* Bz16 = (const unsigned short*)Bv + (CONVB ? 0 : z*sBz);
  const float*          Bz32 = (const float*)Bv + (CONVB ? z*sBz : 0);
  int bm = blockIdx.y*BM, bn = blockIdx.x*BN;
  int bnb = bn;
  int wm = (w>>1)*32, wn = (w&1)*32;

  float4v acc[FM][FN];
  #pragma unroll
  for (int m=0;m<FM;++m)
    #pragma unroll
    for (int n=0;n<FN;++n) acc[m][n] = (float4v){0.f,0.f,0.f,0.f};

  int r = t >> 3, sl = t & 7;      // r in 0..63
  int gc = sl ^ (r & 7);
  int quad = l >> 4, lrow = l & 15;
  const int nit = K >> 6;          // multiple of 4

  int4 Aa0, Aa1, Ab0;  float4 Af0, Af1;
  int4 Ba0, Ba1, Bb0;  float4 Bf0, Bf1;
  int4 Ca0, Ca1, Cb0;  float4 Cf0, Cf1;
  int4 Da0, Da1, Db0;  float4 Df0, Df1;

  auto compute = [&](const char* base) {
    const char* ab = base;
    const char* bb = base + ABYTES;
    #pragma unroll
    for (int step=0; step<2; ++step) {
      int c = step*4 + quad;
      short8 af[FM], bf[FN];
      #pragma unroll
      for (int m=0;m<FM;++m) {
        int Rw = wm + m*16 + lrow;
        af[m] = *(const short8*)(ab + Rw*128 + ((c ^ (Rw & 7))*16));
      }
      #pragma unroll
      for (int n=0;n<FN;++n) {
        int Rw = wn + n*16 + lrow;
        bf[n] = *(const short8*)(bb + Rw*128 + ((c ^ (Rw & 7))*16));
      }
      #pragma unroll
      for (int m=0;m<FM;++m)
        #pragma unroll
        for (int n=0;n<FN;++n)
          acc[m][n] = __builtin_amdgcn_mfma_f32_16x16x32_bf16(af[m], bf[n], acc[m][n], 0, 0, 0);
    }
  };

  LOADSET8(Aa0,Aa1,Ab0,Af0,Af1, 0);
  LOADSET8(Ba0,Ba1,Bb0,Bf0,Bf1, 1);
  LOADSET8(Ca0,Ca1,Cb0,Cf0,Cf1, 2);
  LOADSET8(Da0,Da1,Db0,Df0,Df1, 3);
  for (int it = 0; it < nit; it += 4) {
    STORESET8(lds, Aa0,Aa1,Ab0,Af0,Af1);
    if (it + 4 < nit) LOADSET8(Aa0,Aa1,Ab0,Af0,Af1, it+4);
    lds_barrier();
    compute(lds);
    STORESET8(lds + TILE, Ba0,Ba1,Bb0,Bf0,Bf1);
    if (it + 5 < nit) LOADSET8(Ba0,Ba1,Bb0,Bf0,Bf1, it+5);
    lds_barrier();
    compute(lds + TILE);
    STORESET8(lds, Ca0,Ca1,Cb0,Cf0,Cf1);
    if (it + 6 < nit) LOADSET8(Ca0,Ca1,Cb0,Cf0,Cf1, it+6);
    lds_barrier();
    compute(lds);
    STORESET8(lds + TILE, Da0,Da1,Db0,Df0,Df1);
    if (it + 7 < nit) LOADSET8(Da0,Da1,Db0,Df0,Df1, it+7);
    lds_barrier();
    compute(lds + TILE);
  }

  #pragma unroll
  for (int m=0;m<FM;++m)
    #pragma unroll
    for (int n=0;n<FN;++n)
      #pragma unroll
      for (int rg=0;rg<4;++rg) {
        int row = bm + wm + m*16 + quad*4 + rg;
        int col = bn + wn + n*16 + lrow;
        float vv = acc[m][n][rg];
        if (ZK) {
          atomicAdd(&((float*)Cv)[(size_t)row*ldc + col], vv);
        } else {
          if (HAS_BIAS) vv += bias[col];
          if (HAS_SRC)  vv += src[z*sSz + (size_t)row*ldsrc + col];
          if (RELU) vv = fmaxf(vv, 0.f);
          if (OUT_BF16) ((unsigned short*)Cv)[z*sCz + (size_t)row*ldc + col] = f2bu(vv);
          else          ((float*)Cv)[z*sCz + (size_t)row*ldc + col] = vv;
        }
      }
}

// ------ QKV GEMM 8-wave: fp32 weights direct, BM=128, head-scatter ---------
__global__ __launch_bounds__(512) void gemm_qkv_pl8(
    const unsigned short* __restrict__ A,
    const float* __restrict__ Wq, const float* __restrict__ Wk,
    const float* __restrict__ Wv,
    const float* __restrict__ bq, const float* __restrict__ bk,
    const float* __restrict__ bv,
    unsigned short* __restrict__ Qh, unsigned short* __restrict__ Kh,
    unsigned short* __restrict__ Vt)
{
  constexpr int BN = 64, CONVB = 1;
  constexpr int FM = 2, FN = 2;
  constexpr int ABYTES = 128*128, TILE = ABYTES + BN*128;
  __shared__ char lds[2*TILE];
  int t = threadIdx.x, w = t >> 6, l = t & 63;
  int bm = blockIdx.y*128, bn = blockIdx.x*BN;
  int wm = (w>>1)*32, wn = (w&1)*32;
  const int lda = DD, ldb = DD, nit = DD >> 6;   // 16
  const unsigned short* Az = A;
  int part0 = bn >> 10;
  const float* Bz32 = (part0==0 ? Wq : part0==1 ? Wk : Wv) + (size_t)(bn & 1023)*DD;
  const unsigned short* Bz16 = nullptr; (void)Bz16;
  int bnb = 0;

  float4v acc[FM][FN];
  #pragma unroll
  for (int m=0;m<FM;++m)
    #pragma unroll
    for (int n=0;n<FN;++n) acc[m][n] = (float4v){0.f,0.f,0.f,0.f};

  int r = t >> 3, sl = t & 7;
  int gc = sl ^ (r & 7);
  int quad = l >> 4, lrow = l & 15;

  int4 Aa0, Aa1, Ab0;  float4 Af0, Af1;
  int4 Ba0, Ba1, Bb0;  float4 Bf0, Bf1;
  int4 Ca0, Ca1, Cb0;  float4 Cf0, Cf1;
  int4 Da0, Da1, Db0;  float4 Df0, Df1;

  auto compute = [&](const char* base) {
    const char* ab = base;
    const char* bb = base + ABYTES;
    #pragma unroll
    for (int step=0; step<2; ++step) {
      int c = step*4 + quad;
      short8 af[FM], bf[FN];
      #pragma unroll
      for (int m=0;m<FM;++m) {
        int Rw = wm + m*16 + lrow;
        af[m] = *(const short8*)(ab + Rw*128 + ((c ^ (Rw & 7))*16));
      }
      #pragma unroll
      for (int n=0;n<FN;++n) {
        int Rw = wn + n*16 + lrow;
        bf[n] = *(const short8*)(bb + Rw*128 + ((c ^ (Rw & 7))*16));
      }
      #pragma unroll
      for (int m=0;m<FM;++m)
        #pragma unroll
        for (int n=0;n<FN;++n)
          acc[m][n] = __builtin_amdgcn_mfma_f32_16x16x32_bf16(af[m], bf[n], acc[m][n], 0, 0, 0);
    }
  };

  LOADSET8(Aa0,Aa1,Ab0,Af0,Af1, 0);
  LOADSET8(Ba0,Ba1,Bb0,Bf0,Bf1, 1);
  LOADSET8(Ca0,Ca1,Cb0,Cf0,Cf1, 2);
  LOADSET8(Da0,Da1,Db0,Df0,Df1, 3);
  for (int it = 0; it < nit; it += 4) {
    STORESET8(lds, Aa0,Aa1,Ab0,Af0,Af1);
    if (it + 4 < nit) LOADSET8(Aa0,Aa1,Ab0,Af0,Af1, it+4);
    lds_barrier();
    compute(lds);
    STORESET8(lds + TILE, Ba0,Ba1,Bb0,Bf0,Bf1);
    if (it + 5 < nit) LOADSET8(Ba0,Ba1,Bb0,Bf0,Bf1, it+5);
    lds_barrier();
    compute(lds + TILE);
    STORESET8(lds, Ca0,Ca1,Cb0,Cf0,Cf1);
    if (it + 6 < nit) LOADSET8(Ca0,Ca1,Cb0,Cf0,Cf1, it+6);
    lds_barrier();
    compute(lds);
    STORESET8(lds + TILE, Da0,Da1,Db0,Df0,Df1);
    if (it + 7 < nit) LOADSET8(Da0,Da1,Db0,Df0,Df1, it+7);
    lds_barrier();
    compute(lds + TILE);
  }

  #pragma unroll
  for (int m=0;m<FM;++m)
    #pragma unroll
    for (int n=0;n<FN;++n)
      #pragma unroll
      for (int rg=0;rg<4;++rg) {
        int row = bm + wm + m*16 + quad*4 + rg;
        int col = bn + wn + n*16 + lrow;
        int part = col >> 10, hh = (col >> 7) & 7, d = col & 127;
        const float* bp = (part==0) ? bq : (part==1) ? bk : bv;
        float vv = acc[m][n][rg] + bp[col & 1023];
        unsigned short o = f2bu(vv);
        if (part == 0)      Qh[((size_t)hh*LL + row)*DKK + d] = o;
        else if (part == 1) Kh[(((size_t)hh*16 + (d>>3))*KLD + row)*8 + (d&7)] = o;
        else                Vt[(((size_t)hh*64 + (row>>3))*128 + d)*8 + (row&7)] = o;
      }
}

// ======== fused attention v3: direct-global K/V MFMA operands, 4 barriers ====
// grid (64,8), 256 thr. K/V in slice-major layout -> B-fragments load coalesced
// straight from L2; no K/V LDS staging at all.
// LDS map (bytes):
//   [0    , 2176 )  Qt   [8][136]  bf16 (stride 272)
//   [2176 , 10496)  P    [8][520]  bf16 (stride 1040)
//   [10496, 29184)  S    [8][584]  f32  (stride 2336 B)
//   [29184, 30848)  pws  [8][52]   f32
//   [30848, 30976)  pf1  [8][4]    f32
//   [30976, 31104)  pf2  [8][4]    f32
//   [31104, 31136)  sinv [8]       f32
//   [31136, 35360)  o2s  [8][132]  f32
#define A3_QROWB 272
#define A3_PROWB 1040
#define A3_SROWD 584
#define A3_O2ROW 132
#define A3_OFF_P   2176
#define A3_OFF_S   10496
#define A3_OFF_PW  29184
#define A3_OFF_PF1 30848
#define A3_OFF_PF2 30976
#define A3_OFF_SI  31104
#define A3_OFF_O2  31136
#define A3_LDS     35360

__global__ __launch_bounds__(256) void attn_fused(
    const unsigned short* __restrict__ Qh, const unsigned short* __restrict__ Kh,
    const unsigned short* __restrict__ Vt,
    const float* __restrict__ qcr, const float* __restrict__ cqr,
    const float* __restrict__ qtr, const float* __restrict__ tqr,
    const int* __restrict__ ct, const int* __restrict__ pred,
    const int* __restrict__ mask,
    const float* __restrict__ embv, const float* __restrict__ lqc_v,
    const float* __restrict__ lcq_v, const float* __restrict__ lqt_v,
    const float* __restrict__ ltq_v,
    unsigned short* __restrict__ obuf)
{
  __shared__ __align__(16) char lds[A3_LDS];
  const int t = threadIdx.x;
  const int w = t >> 6, l = t & 63, quad = l >> 4, lrow = l & 15;
  const int i0 = blockIdx.x * 8, h = blockIdx.y;

  // zero pws/pf/sinv region (488 floats)
  for (int k2 = t; k2 < 488; k2 += 256) ((float*)(lds + A3_OFF_PW))[k2] = 0.f;

  // stage Q tile [8][128]
  if (t < 128) {
    int qr = t >> 4, qc = t & 15;
    *(int4*)(lds + qr*A3_QROWB + qc*16) =
        *(const int4*)(Qh + ((size_t)h*LL + i0 + qr)*DKK + qc*8);
  }
  lds_barrier();    // barrier 1: Qt + zeroed pws visible

  // ---- phase 1: S[8][576] = Q @ Kh^T, K fragments direct from global ----
  {
    const unsigned short* Kc = Kh + (size_t)h*16*KLD*8;
    short8 af0 = *(const short8*)(lds + lrow*A3_QROWB + (quad     )*16);
    short8 af1 = *(const short8*)(lds + lrow*A3_QROWB + (quad +  4)*16);
    short8 af2 = *(const short8*)(lds + lrow*A3_QROWB + (quad +  8)*16);
    short8 af3 = *(const short8*)(lds + lrow*A3_QROWB + (quad + 12)*16);
    #pragma unroll
    for (int jt = 0; jt < 9; ++jt) {
      float4v acc = (float4v){0.f,0.f,0.f,0.f};
      int krow = jt*64 + w*16 + lrow;
      short8 bf0 = *(const short8*)(Kc + ((size_t)(quad     )*KLD + krow)*8);
      short8 bf1 = *(const short8*)(Kc + ((size_t)(quad +  4)*KLD + krow)*8);
      short8 bf2 = *(const short8*)(Kc + ((size_t)(quad +  8)*KLD + krow)*8);
      short8 bf3 = *(const short8*)(Kc + ((size_t)(quad + 12)*KLD + krow)*8);
      acc = __builtin_amdgcn_mfma_f32_16x16x32_bf16(af0, bf0, acc, 0, 0, 0);
      acc = __builtin_amdgcn_mfma_f32_16x16x32_bf16(af1, bf1, acc, 0, 0, 0);
      acc = __builtin_amdgcn_mfma_f32_16x16x32_bf16(af2, bf2, acc, 0, 0, 0);
      acc = __builtin_amdgcn_mfma_f32_16x16x32_bf16(af3, bf3, acc, 0, 0, 0);
      if (quad < 2) {
        #pragma unroll
        for (int rg = 0; rg < 4; ++rg)
          ((float*)(lds + A3_OFF_S))[(quad*4 + rg)*A3_SROWD + jt*64 + w*16 + lrow] = acc[rg];
      }
    }
  }
  lds_barrier();    // barrier 2: S visible

  // ---- phase 2: single-pass unnormalized softmax (32 lanes per row) ----
  const int row = t >> 5, l32 = t & 31;
  const int i = i0 + row;
  const float* Sp = (const float*)(lds + A3_OFF_S) + row*A3_SROWD;
  const int bse = (i0 < QQ) ? 562 : (i0 < QQ + CCC) ? 568 : 571;
  const float lq1a = Sp[bse], lq1b = Sp[bse+1], lq1c = Sp[bse+2];
  const float lq2a = Sp[565], lq2b = Sp[566], lq2c = Sp[567];

  float sum=0.f, f0=0.f, f1=0.f, f2=0.f, g0=0.f, g1=0.f, g2=0.f;
  float* pwsrow = (float*)(lds + A3_OFF_PW) + row*52;
  #pragma unroll
  for (int m = 0; m < 16; ++m) {
    int j = m*32 + l32;
    int predv = pred[i*LL + j];
    int maskv = mask[i*LL + j];
    float s = Sp[j] + Sp[512 + predv];
    float c0=0.f, c1=0.f, c2=0.f; int rt; int scat2 = 0;
    if (i0 < QQ) {
      if (j < QQ) { s += Sp[512]; rt = 0; }
      else if (j < QQ + CCC) {
        const float* r3 = qcr + ((size_t)i*CCC + (j - QQ))*3;
        c0 = r3[0]; c1 = r3[1]; c2 = r3[2];
        s += c0*lq1a + c1*lq1b + c2*lq1c; rt = 1;
      } else {
        const float* r3 = qtr + ((size_t)i*TTT + (j - QQ - CCC))*3;
        c0 = r3[0]; c1 = r3[1]; c2 = r3[2];
        s += c0*lq2a + c1*lq2b + c2*lq2c; rt = 2;
      }
    } else {
      if (j < QQ) {
        const float* r3 = (i < QQ + CCC) ? cqr + ((size_t)(i - QQ)*QQ + j)*3
                                         : tqr + ((size_t)(i - QQ - CCC)*QQ + j)*3;
        c0 = r3[0]; c1 = r3[1]; c2 = r3[2];
        s += c0*lq1a + c1*lq1b + c2*lq1c; rt = 1;
      } else {
        scat2 = ct[(i - QQ)*(CCC + TTT) + (j - QQ)];
        s += Sp[512 + scat2]; rt = 0;
      }
    }
    s *= 0.08838834764831845f;
    float e = (maskv == 0) ? 0.f : __expf(s);
    sum += e;
    *(unsigned short*)(lds + A3_OFF_P + row*A3_PROWB + j*2) = f2bu(e);
    atomicAdd(pwsrow + predv, e);
    if (rt == 0)      atomicAdd(pwsrow + scat2, e);
    else if (rt == 1) { f0 += e*c0; f1 += e*c1; f2 += e*c2; }
    else              { g0 += e*c0; g1 += e*c1; g2 += e*c2; }
  }
  #pragma unroll
  for (int off = 16; off >= 1; off >>= 1) {
    sum += __shfl_xor(sum, off);
    f0 += __shfl_xor(f0, off); f1 += __shfl_xor(f1, off); f2 += __shfl_xor(f2, off);
    g0 += __shfl_xor(g0, off); g1 += __shfl_xor(g1, off); g2 += __shfl_xor(g2, off);
  }
  if (l32 == 0) {
    float* pf1 = (float*)(lds + A3_OFF_PF1) + row*4;
    float* pf2 = (float*)(lds + A3_OFF_PF2) + row*4;
    pf1[0] = f0; pf1[1] = f1; pf1[2] = f2;
    pf2[0] = g0; pf2[1] = g1; pf2[2] = g2;
    ((float*)(lds + A3_OFF_SI))[row] = 1.0f / sum;
  }
  lds_barrier();    // barrier 3: P/pws/pf/sinv visible; S reads done

  // ---- o2term: o2s[row][d] = pws@embv + pf@tables (f32), per-thread (row,d) ----
  {
    int orow = t >> 5, d0 = (t & 31)*4;
    const float* pwsr = (const float*)(lds + A3_OFF_PW) + orow*52;
    float a0=0.f, a1=0.f, a2=0.f, a3=0.f;
    #pragma unroll 5
    for (int rr = 0; rr < RR; ++rr) {
      float pv = pwsr[rr];
      float4 ev = *(const float4*)(embv + rr*DKK + d0);
      a0 += pv*ev.x; a1 += pv*ev.y; a2 += pv*ev.z; a3 += pv*ev.w;
    }
    const float* tab1 = (i0 < QQ) ? lqc_v : (i0 < QQ + CCC) ? lcq_v : ltq_v;
    const float* pf1 = (const float*)(lds + A3_OFF_PF1) + orow*4;
    float4 t0 = *(const float4*)(tab1 + d0);
    float4 t1 = *(const float4*)(tab1 + DKK + d0);
    float4 t2 = *(const float4*)(tab1 + 2*DKK + d0);
    a0 += pf1[0]*t0.x + pf1[1]*t1.x + pf1[2]*t2.x;
    a1 += pf1[0]*t0.y + pf1[1]*t1.y + pf1[2]*t2.y;
    a2 += pf1[0]*t0.z + pf1[1]*t1.z + pf1[2]*t2.z;
    a3 += pf1[0]*t0.w + pf1[1]*t1.w + pf1[2]*t2.w;
    if (i0 < QQ) {
      const float* pf2 = (const float*)(lds + A3_OFF_PF2) + orow*4;
      float4 u0 = *(const float4*)(lqt_v + d0);
      float4 u1 = *(const float4*)(lqt_v + DKK + d0);
      float4 u2 = *(const float4*)(lqt_v + 2*DKK + d0);
      a0 += pf2[0]*u0.x + pf2[1]*u1.x + pf2[2]*u2.x;
      a1 += pf2[0]*u0.y + pf2[1]*u1.y + pf2[2]*u2.y;
      a2 += pf2[0]*u0.z + pf2[1]*u1.z + pf2[2]*u2.z;
      a3 += pf2[0]*u0.w + pf2[1]*u1.w + pf2[2]*u2.w;
    }
    float4 av; av.x=a0; av.y=a1; av.z=a2; av.w=a3;
    *(float4*)((float*)(lds + A3_OFF_O2) + orow*A3_O2ROW + d0) = av;
  }
  lds_barrier();    // barrier 4: o2s visible

  // ---- phase 3: O[8][128] = E @ V^T, V fragments direct from global; no barriers ----
  float4v oacc0 = (float4v){0.f,0.f,0.f,0.f};
  float4v oacc1 = (float4v){0.f,0.f,0.f,0.f};
  {
    const unsigned short* Vc = Vt + (size_t)h*64*128*8;
    #pragma unroll
    for (int it = 0; it < 8; ++it) {
      #pragma unroll
      for (int kk = 0; kk < 2; ++kk) {
        int c = kk*4 + quad;
        short8 pa  = *(const short8*)(lds + A3_OFF_P + lrow*A3_PROWB + it*128 + c*16);
        short8 vf0 = *(const short8*)(Vc + (((size_t)(it*8 + c))*128 + w*32 + lrow)*8);
        short8 vf1 = *(const short8*)(Vc + (((size_t)(it*8 + c))*128 + w*32 + 16 + lrow)*8);
        oacc0 = __builtin_amdgcn_mfma_f32_16x16x32_bf16(pa, vf0, oacc0, 0, 0, 0);
        oacc1 = __builtin_amdgcn_mfma_f32_16x16x32_bf16(pa, vf1, oacc1, 0, 0, 0);
      }
    }
  }

  // ---- epilogue: (oacc + o2s) * sinv -> obuf bf16 ----
  if (quad < 2) {
    const float* o2s = (const float*)(lds + A3_OFF_O2);
    const float* sinv = (const float*)(lds + A3_OFF_SI);
    #pragma unroll
    for (int n = 0; n < 2; ++n) {
      int d = w*32 + n*16 + lrow;
      #pragma unroll
      for (int rg = 0; rg < 4; ++rg) {
        int rw = quad*4 + rg;
        float oval = (n==0) ? oacc0[rg] : oacc1[rg];
        float val = (oval + o2s[rw*A3_O2ROW + d]) * sinv[rw];
        obuf[(size_t)(i0 + rw)*DD + h*DKK + d] = f2bu(val);
      }
    }
  }
}

// ---------------- launch ----------------
extern "C" void kernel_launch(void* const* d_in, const int* in_sizes, int n_in,
                              void* d_out, int out_size, void* d_ws, size_t ws_size,
                              hipStream_t stream)
{
  const float* x    = (const float*)d_in[0];
  const float* qcr  = (const float*)d_in[1];
  const float* cqr  = (const float*)d_in[2];
  const float* qtr  = (const float*)d_in[3];
  const float* tqr  = (const float*)d_in[4];
  const int*   ct   = (const int*)d_in[5];
  const int*   pred = (const int*)d_in[6];
  const int*   mask = (const int*)d_in[7];
  const float* embk = (const float*)d_in[8];
  const float* embv = (const float*)d_in[9];
  const float* lqc_k = (const float*)d_in[10];
  const float* lqc_v = (const float*)d_in[11];
  const float* lcq_k = (const float*)d_in[12];
  const float* lcq_v = (const float*)d_in[13];
  const float* lqt_k = (const float*)d_in[14];
  const float* lqt_v = (const float*)d_in[15];
  const float* ltq_k = (const float*)d_in[16];
  const float* ltq_v = (const float*)d_in[17];
  const float* Wq = (const float*)d_in[18]; const float* bq = (const float*)d_in[19];
  const float* Wk = (const float*)d_in[20]; const float* bk = (const float*)d_in[21];
  const float* Wv = (const float*)d_in[22]; const float* bv = (const float*)d_in[23];
  const float* Wo = (const float*)d_in[24]; const float* bo = (const float*)d_in[25];
  const float* ln1_g = (const float*)d_in[26]; const float* ln1_b = (const float*)d_in[27];
  const float* ln2_g = (const float*)d_in[28]; const float* ln2_b = (const float*)d_in[29];
  const float* W1 = (const float*)d_in[30]; const float* b1 = (const float*)d_in[31];
  const float* W2 = (const float*)d_in[32]; const float* b2 = (const float*)d_in[33];
  float* out = (float*)d_out;

  float* wsf = (float*)d_ws;
  float* S    = wsf;                          // FFN hidden region (attention no longer uses it)
  float* o2   = S + (size_t)HH*LL*SLD;        // kept for layout stability (unused)
  unsigned short* ub = (unsigned short*)(o2 + (size_t)HH*LL*DKK);
  unsigned short* ybuf_b = ub;                        // [L,D]
  unsigned short* obuf_b = ybuf_b + LL*DD;            // [L,D]
  unsigned short* Qh     = obuf_b + LL*DD;            // [H][512][128]
  unsigned short* Kh     = Qh + (size_t)HH*LL*DKK;    // [H][16][576][8] slice-major
  unsigned short* Vt     = Kh + (size_t)HH*KLD*DKK;   // [H][64][128][8] slice-major
  unsigned short* hidden = (unsigned short*)S;        // [L][FFF] bf16

  // 1. LN1 -> bf16 (+ fused kprep: Kh rows 512..575)
  ln_bf16_kernel<<<LL, 256, 0, stream>>>(x, ln1_g, ln1_b, ybuf_b,
                                         embk, lqc_k, lqt_k, lcq_k, ltq_k, Kh);
  // 2. QKV GEMM (8-wave BM=128, fp32 weights direct) with head scatter
  gemm_qkv_pl8<<<dim3(48, 4), 512, 0, stream>>>(ybuf_b, Wq, Wk, Wv, bq, bk, bv,
                                                Qh, Kh, Vt);
  // 3. fused attention v3: direct-global K/V, 4 barriers
  attn_fused<<<dim3(64, 8), 256, 0, stream>>>(
      Qh, Kh, Vt, qcr, cqr, qtr, tqr, ct, pred, mask,
      embv, lqc_v, lcq_v, lqt_v, ltq_v, obuf_b);
  // 4. out-proj (fp32 Wo direct, depth-4) + residual(x) -> out
  gemm_pl<32,4,1,0,0,0,1,1><<<dim3(32, 8, 1), 256, 0, stream>>>(
      obuf_b, DD, 0, Wo, DD, 0, bo, x, DD, 0, out, DD, 0, DD);
  // 5. LN2 -> bf16, and out += b2 (split-K init)
  ln_bf16_addb_kernel<<<LL, 256, 0, stream>>>(out, ln2_g, ln2_b, b2, ybuf_b);
  // 6. FFN1 relu (8-wave BM=128, fp32 W1 direct) -> hidden bf16
  gemm_pl8<64,1,0,1,1,0,1><<<dim3(64, 4), 512, 0, stream>>>(
      ybuf_b, DD, 0, W1, DD, 0, b1, nullptr, 0, 0, hidden, FFF, 0, DD);
  // 7. FFN2 split-K x4 (8-wave BM=128, fp32 W2 direct), atomicAdd -> out
  gemm_pl8<64,1,1,0,0,0,0><<<dim3(16, 4, 4), 512, 0, stream>>>(
      hidden, FFF, (size_t)1024, W2, FFF, (size_t)1024,
      nullptr, nullptr, 0, 0, out, DD, 0, 1024);
}